// Round 1
// baseline (3241.013 us; speedup 1.0000x reference)
//
#include <hip/hip_runtime.h>
#include <math.h>
#include <stdio.h>

#define N_SRC 200000
#define N_DST 100000
#define NE    400000
// IN=128, H=8, D=32, H*D=256

// ---------------------------------------------------------------------------
// Tiled f32 GEMM: out[n][c] = sum_k A[n][k]*W[c][k] + bias[c] + add_n[n][c] + add_c[c]
// A: [N,K] row-major, W: [C,K] row-major. C must be a multiple of 128.
// Block: 256 threads computes 64 rows x 128 cols. BK=16.
// ---------------------------------------------------------------------------
__global__ __launch_bounds__(256) void gemm_atb(
    const float* __restrict__ A, const float* __restrict__ W,
    const float* __restrict__ bias, const float* __restrict__ add_n,
    const float* __restrict__ add_c, float* __restrict__ out,
    int N, int K, int C)
{
    __shared__ float As[16][68];   // [k][row], padded
    __shared__ float Ws[16][132];  // [k][col], padded

    const int tid = threadIdx.x;
    const int tx  = tid & 15;      // col group (8 cols each)
    const int ty  = tid >> 4;      // row group (4 rows each)
    const int n0  = blockIdx.y * 64;
    const int c0  = blockIdx.x * 128;

    float acc[4][8];
#pragma unroll
    for (int r = 0; r < 4; ++r)
#pragma unroll
        for (int c = 0; c < 8; ++c) acc[r][c] = 0.f;

    const int a_row = tid >> 2;        // 0..63
    const int a_k4  = (tid & 3) * 4;   // 0,4,8,12
    const int w_col = tid >> 1;        // 0..127
    const int w_k8  = (tid & 1) * 8;   // 0 or 8

    for (int k0 = 0; k0 < K; k0 += 16) {
        // ---- load A tile (64 x 16) ----
        {
            int n = n0 + a_row;
            float4 va = make_float4(0.f, 0.f, 0.f, 0.f);
            if (n < N) {
                int k = k0 + a_k4;
                if (k + 3 < K) {
                    va = *(const float4*)&A[(long)n * K + k];
                } else {
                    float t[4] = {0.f, 0.f, 0.f, 0.f};
                    for (int j = 0; j < 4; ++j) if (k + j < K) t[j] = A[(long)n * K + k + j];
                    va = make_float4(t[0], t[1], t[2], t[3]);
                }
            }
            As[a_k4 + 0][a_row] = va.x;
            As[a_k4 + 1][a_row] = va.y;
            As[a_k4 + 2][a_row] = va.z;
            As[a_k4 + 3][a_row] = va.w;
        }
        // ---- load W tile (128 x 16) ----
        {
            int c = c0 + w_col;
#pragma unroll
            for (int half = 0; half < 2; ++half) {
                int k = k0 + w_k8 + half * 4;
                float4 vw = make_float4(0.f, 0.f, 0.f, 0.f);
                if (k + 3 < K) {
                    vw = *(const float4*)&W[(long)c * K + k];
                } else {
                    float t[4] = {0.f, 0.f, 0.f, 0.f};
                    for (int j = 0; j < 4; ++j) if (k + j < K) t[j] = W[(long)c * K + k + j];
                    vw = make_float4(t[0], t[1], t[2], t[3]);
                }
                Ws[w_k8 + half * 4 + 0][w_col] = vw.x;
                Ws[w_k8 + half * 4 + 1][w_col] = vw.y;
                Ws[w_k8 + half * 4 + 2][w_col] = vw.z;
                Ws[w_k8 + half * 4 + 3][w_col] = vw.w;
            }
        }
        __syncthreads();
#pragma unroll
        for (int kk = 0; kk < 16; ++kk) {
            float4 a  = *(const float4*)&As[kk][ty * 4];
            float4 w0 = *(const float4*)&Ws[kk][tx * 8];
            float4 w1 = *(const float4*)&Ws[kk][tx * 8 + 4];
            float av[4] = {a.x, a.y, a.z, a.w};
            float wv[8] = {w0.x, w0.y, w0.z, w0.w, w1.x, w1.y, w1.z, w1.w};
#pragma unroll
            for (int r = 0; r < 4; ++r)
#pragma unroll
                for (int c = 0; c < 8; ++c)
                    acc[r][c] += av[r] * wv[c];
        }
        __syncthreads();
    }

#pragma unroll
    for (int r = 0; r < 4; ++r) {
        int n = n0 + ty * 4 + r;
        if (n >= N) continue;
#pragma unroll
        for (int c = 0; c < 8; ++c) {
            int cc = c0 + tx * 8 + c;
            float val = acc[r][c];
            if (bias)  val += bias[cc];
            if (add_c) val += add_c[cc];
            if (add_n) val += add_n[(long)n * C + cc];
            out[(long)n * C + cc] = val;
        }
    }
}

// ---------------------------------------------------------------------------
// Fold W_na into Q/K projections: Weff[h][k] = sum_d W[(h*32+d)*128+k]*na[d]
// ---------------------------------------------------------------------------
__global__ void eff_setup(const float* __restrict__ Wq, const float* __restrict__ bq,
                          const float* __restrict__ na_item,
                          const float* __restrict__ Wk, const float* __restrict__ bk,
                          const float* __restrict__ na_user,
                          float* __restrict__ wq_eff, float* __restrict__ bq_eff,
                          float* __restrict__ wk_eff, float* __restrict__ bk_eff)
{
    int tid = threadIdx.x;
    for (int idx = tid; idx < 1024; idx += 256) {
        int h = idx >> 7, k = idx & 127;
        float s1 = 0.f, s2 = 0.f;
        for (int d = 0; d < 32; ++d) {
            s1 += Wq[(h * 32 + d) * 128 + k] * na_item[d];
            s2 += Wk[(h * 32 + d) * 128 + k] * na_user[d];
        }
        wq_eff[idx] = s1;
        wk_eff[idx] = s2;
    }
    if (tid < 8) {
        float s1 = 0.f, s2 = 0.f;
        for (int d = 0; d < 32; ++d) {
            s1 += bq[tid * 32 + d] * na_item[d];
            s2 += bk[tid * 32 + d] * na_user[d];
        }
        bq_eff[tid] = s1;
        bk_eff[tid] = s2;
    }
}

// ---------------------------------------------------------------------------
// Wave-per-row: out[n][h] = sum_k feat[n][k]*weff[h][k] + beff[h], h<8, k<128
// ---------------------------------------------------------------------------
__global__ __launch_bounds__(256) void rowdot8_kernel(
    const float* __restrict__ feat, const float* __restrict__ weff,
    const float* __restrict__ beff, float* __restrict__ out, int N)
{
    int gw   = (blockIdx.x * blockDim.x + threadIdx.x) >> 6;
    int lane = threadIdx.x & 63;
    if (gw >= N) return;
    int c = lane * 2;
    float2 x = *(const float2*)&feat[(long)gw * 128 + c];
    float part[8];
#pragma unroll
    for (int h = 0; h < 8; ++h)
        part[h] = x.x * weff[h * 128 + c] + x.y * weff[h * 128 + c + 1];
#pragma unroll
    for (int h = 0; h < 8; ++h) {
#pragma unroll
        for (int off = 32; off > 0; off >>= 1) part[h] += __shfl_xor(part[h], off);
    }
#pragma unroll
    for (int h = 0; h < 8; ++h)
        if (lane == h) out[(long)gw * 8 + h] = part[h] + beff[h];
}

// ---------------------------------------------------------------------------
// Wave-per-edge: z[e][c] = exp(ef[e][c] + src_feat[src[e]][c]) (in place on efz),
// atomic segment sum into s1[dst][c].
// ---------------------------------------------------------------------------
__global__ __launch_bounds__(256) void zs_kernel(
    float* __restrict__ efz, const float* __restrict__ src_feat,
    const int* __restrict__ src_idx, const int* __restrict__ dst_idx,
    float* __restrict__ s1)
{
    int gw   = (blockIdx.x * blockDim.x + threadIdx.x) >> 6;
    int lane = threadIdx.x & 63;
    if (gw >= NE) return;
    int src = src_idx[gw], dst = dst_idx[gw];
    int c = lane * 2;
    float2 e2 = *(const float2*)&efz[(long)gw * 128 + c];
    float2 f2 = *(const float2*)&src_feat[(long)src * 128 + c];
    float zx = expf(e2.x + f2.x);
    float zy = expf(e2.y + f2.y);
    *(float2*)&efz[(long)gw * 128 + c] = make_float2(zx, zy);
    atomicAdd(&s1[(long)dst * 128 + c], zx);
    atomicAdd(&s1[(long)dst * 128 + c + 1], zy);
}

// ---------------------------------------------------------------------------
// Wave-per-edge: temp_attn[e][h] = sum_c (z[e][c]/s1[dst][c]) * W_eattn[h][c] + b[h]
// ---------------------------------------------------------------------------
__global__ __launch_bounds__(256) void tattn_kernel(
    const float* __restrict__ z, const float* __restrict__ s1,
    const int* __restrict__ dst_idx, const float* __restrict__ W_eattn,
    const float* __restrict__ b_eattn, float* __restrict__ tattn)
{
    int gw   = (blockIdx.x * blockDim.x + threadIdx.x) >> 6;
    int lane = threadIdx.x & 63;
    if (gw >= NE) return;
    int dst = dst_idx[gw];
    int c = lane * 2;
    float2 zr = *(const float2*)&z[(long)gw * 128 + c];
    float2 sr = *(const float2*)&s1[(long)dst * 128 + c];
    float t0 = zr.x / sr.x;
    float t1 = zr.y / sr.y;
    float part[8];
#pragma unroll
    for (int h = 0; h < 8; ++h)
        part[h] = t0 * W_eattn[h * 128 + c] + t1 * W_eattn[h * 128 + c + 1];
#pragma unroll
    for (int h = 0; h < 8; ++h) {
#pragma unroll
        for (int off = 32; off > 0; off >>= 1) part[h] += __shfl_xor(part[h], off);
    }
#pragma unroll
    for (int h = 0; h < 8; ++h)
        if (lane == h) tattn[(long)gw * 8 + h] = part[h] + b_eattn[h];
}

// ---------------------------------------------------------------------------
// Thread-per-edge: z2[e][h] = exp((ak[src][h]+aq[dst][h])/sqrt(32)); atomic s2.
// ---------------------------------------------------------------------------
__global__ void z2s2_kernel(const float* __restrict__ ak, const float* __restrict__ aq,
                            const int* __restrict__ src_idx, const int* __restrict__ dst_idx,
                            float* __restrict__ z2, float* __restrict__ s2)
{
    int e = blockIdx.x * blockDim.x + threadIdx.x;
    if (e >= NE) return;
    int src = src_idx[e], dst = dst_idx[e];
    const float rs = 0.17677669529663687f;  // 1/sqrt(32)
    float4 k0 = *(const float4*)&ak[(long)src * 8];
    float4 k1 = *(const float4*)&ak[(long)src * 8 + 4];
    float4 q0 = *(const float4*)&aq[(long)dst * 8];
    float4 q1 = *(const float4*)&aq[(long)dst * 8 + 4];
    float z[8];
    z[0] = expf((k0.x + q0.x) * rs);
    z[1] = expf((k0.y + q0.y) * rs);
    z[2] = expf((k0.z + q0.z) * rs);
    z[3] = expf((k0.w + q0.w) * rs);
    z[4] = expf((k1.x + q1.x) * rs);
    z[5] = expf((k1.y + q1.y) * rs);
    z[6] = expf((k1.z + q1.z) * rs);
    z[7] = expf((k1.w + q1.w) * rs);
    *(float4*)&z2[(long)e * 8]     = make_float4(z[0], z[1], z[2], z[3]);
    *(float4*)&z2[(long)e * 8 + 4] = make_float4(z[4], z[5], z[6], z[7]);
#pragma unroll
    for (int h = 0; h < 8; ++h) atomicAdd(&s2[(long)dst * 8 + h], z[h]);
}

// ---------------------------------------------------------------------------
// Wave-per-edge: merged[h] = W_merge[h][:] . [self_attn, temp_attn] + b_merge[h];
// agg[dst][oc] += merged[oc/32] * v[src][oc]  (atomic scatter, oc = lane*4..+3)
// ---------------------------------------------------------------------------
__global__ __launch_bounds__(256) void mergeagg_kernel(
    const float* __restrict__ z2, const float* __restrict__ s2,
    const float* __restrict__ tattn, const float* __restrict__ W_merge,
    const float* __restrict__ b_merge, const float* __restrict__ v,
    const int* __restrict__ src_idx, const int* __restrict__ dst_idx,
    float* __restrict__ agg)
{
    int gw   = (blockIdx.x * blockDim.x + threadIdx.x) >> 6;
    int lane = threadIdx.x & 63;
    if (gw >= NE) return;
    int src = src_idx[gw], dst = dst_idx[gw];
    int h = lane & 7;  // lanes 0..7 hold merged[0..7]
    float m = b_merge[h];
#pragma unroll
    for (int j = 0; j < 8; ++j)
        m += W_merge[h * 16 + j] * (z2[(long)gw * 8 + j] / s2[(long)dst * 8 + j]);
#pragma unroll
    for (int j = 0; j < 8; ++j)
        m += W_merge[h * 16 + 8 + j] * tattn[(long)gw * 8 + j];
    float mm = __shfl(m, lane >> 3);   // merged for this lane's head = oc/32
    float4 vv = *(const float4*)&v[(long)src * 256 + lane * 4];
    float* o = agg + (long)dst * 256 + lane * 4;
    atomicAdd(o + 0, vv.x * mm);
    atomicAdd(o + 1, vv.y * mm);
    atomicAdd(o + 2, vv.z * mm);
    atomicAdd(o + 3, vv.w * mm);
}

// ---------------------------------------------------------------------------
// Wave-per-row LayerNorm over 256, in place.
// ---------------------------------------------------------------------------
__global__ __launch_bounds__(256) void ln_kernel(float* __restrict__ io,
    const float* __restrict__ gamma, const float* __restrict__ beta)
{
    int gw   = (blockIdx.x * blockDim.x + threadIdx.x) >> 6;
    int lane = threadIdx.x & 63;
    if (gw >= N_DST) return;
    float4 x = *(const float4*)&io[(long)gw * 256 + lane * 4];
    float s = x.x + x.y + x.z + x.w;
    float q = x.x * x.x + x.y * x.y + x.z * x.z + x.w * x.w;
#pragma unroll
    for (int off = 32; off > 0; off >>= 1) {
        s += __shfl_xor(s, off);
        q += __shfl_xor(q, off);
    }
    float mu  = s * (1.0f / 256.0f);
    float var = q * (1.0f / 256.0f) - mu * mu;
    float inv = rsqrtf(var + 1e-5f);
    float4 g = *(const float4*)&gamma[lane * 4];
    float4 b = *(const float4*)&beta[lane * 4];
    float4 o;
    o.x = (x.x - mu) * inv * g.x + b.x;
    o.y = (x.y - mu) * inv * g.y + b.y;
    o.z = (x.z - mu) * inv * g.z + b.z;
    o.w = (x.w - mu) * inv * g.w + b.w;
    *(float4*)&io[(long)gw * 256 + lane * 4] = o;
}

// ---------------------------------------------------------------------------
extern "C" void kernel_launch(void* const* d_in, const int* in_sizes, int n_in,
                              void* d_out, int out_size, void* d_ws, size_t ws_size,
                              hipStream_t stream)
{
    const float* x_user        = (const float*)d_in[0];
    const float* x_item        = (const float*)d_in[1];
    const float* node_emb_user = (const float*)d_in[2];
    const float* edge_emb      = (const float*)d_in[3];
    const float* edge_feats    = (const float*)d_in[4];
    const int*   src_idx       = (const int*)d_in[5];
    const int*   dst_idx       = (const int*)d_in[6];
    const float* W_nf_user     = (const float*)d_in[7];
    const float* b_nf_user     = (const float*)d_in[8];
    const float* W_nf_item     = (const float*)d_in[9];
    const float* b_nf_item     = (const float*)d_in[10];
    const float* W_ef          = (const float*)d_in[11];
    const float* b_ef          = (const float*)d_in[12];
    const float* W_eattn       = (const float*)d_in[13];
    const float* b_eattn       = (const float*)d_in[14];
    const float* W_merge       = (const float*)d_in[15];
    const float* b_merge       = (const float*)d_in[16];
    const float* W_q           = (const float*)d_in[17];
    const float* b_q           = (const float*)d_in[18];
    const float* W_k           = (const float*)d_in[19];
    const float* b_k           = (const float*)d_in[20];
    const float* W_v           = (const float*)d_in[21];
    const float* b_v           = (const float*)d_in[22];
    const float* W_na_user     = (const float*)d_in[23];
    const float* W_na_item     = (const float*)d_in[24];
    const float* ln_gamma      = (const float*)d_in[25];
    const float* ln_beta       = (const float*)d_in[26];

    float* ws = (float*)d_ws;
    float* src_feat = ws;                        // 25,600,000
    float* dst_feat = src_feat + 25600000;       // 12,800,000
    float* efz      = dst_feat + 12800000;       // 51,200,000 (ef, then z in place)
    float* s1       = efz + 51200000;            // 12,800,000
    float* tattn    = s1 + 12800000;             //  3,200,000
    float* aq       = tattn + 3200000;           //    800,000
    float* ak       = aq + 800000;               //  1,600,000
    float* vbuf     = ak + 1600000;              // 51,200,000
    float* z2       = vbuf + 51200000;           //  3,200,000
    float* s2       = z2 + 3200000;              //    800,000
    float* wq_eff   = s2 + 800000;               //      1,024
    float* wk_eff   = wq_eff + 1024;             //      1,024
    float* bq_eff   = wk_eff + 1024;             //         16
    float* bk_eff   = bq_eff + 16;               //         16
    size_t needed = (size_t)(bk_eff + 16 - ws) * sizeof(float);
    if (ws_size < needed) {
        fprintf(stderr, "kernel_launch: ws_size %zu < needed %zu\n", ws_size, needed);
        return;
    }

    // zero the accumulators (harness does not re-poison between replays)
    hipMemsetAsync(s1, 0, 12800000 * sizeof(float), stream);
    hipMemsetAsync(s2, 0, 800000 * sizeof(float), stream);
    hipMemsetAsync(d_out, 0, (size_t)out_size * sizeof(float), stream);

    eff_setup<<<1, 256, 0, stream>>>(W_q, b_q, W_na_item, W_k, b_k, W_na_user,
                                     wq_eff, bq_eff, wk_eff, bk_eff);

    // src_feat = x_user @ W_nf_user^T + b + node_emb_user + edge_emb
    gemm_atb<<<dim3(1, 3125), 256, 0, stream>>>(x_user, W_nf_user, b_nf_user,
                                                node_emb_user, edge_emb, src_feat,
                                                N_SRC, 300, 128);
    // dst_feat = x_item @ W_nf_item^T + b + edge_emb
    gemm_atb<<<dim3(1, 1563), 256, 0, stream>>>(x_item, W_nf_item, b_nf_item,
                                                nullptr, edge_emb, dst_feat,
                                                N_DST, 200, 128);
    // ef = edge_feats @ W_ef^T + b_ef
    gemm_atb<<<dim3(1, 6250), 256, 0, stream>>>(edge_feats, W_ef, b_ef,
                                                nullptr, nullptr, efz,
                                                NE, 64, 128);
    // v = src_feat @ W_v^T + b_v
    gemm_atb<<<dim3(2, 3125), 256, 0, stream>>>(src_feat, W_v, b_v,
                                                nullptr, nullptr, vbuf,
                                                N_SRC, 128, 256);
    // aq / ak via folded weights
    rowdot8_kernel<<<25000, 256, 0, stream>>>(dst_feat, wq_eff, bq_eff, aq, N_DST);
    rowdot8_kernel<<<50000, 256, 0, stream>>>(src_feat, wk_eff, bk_eff, ak, N_SRC);

    // softmax #1 numerator + denominators
    zs_kernel<<<100000, 256, 0, stream>>>(efz, src_feat, src_idx, dst_idx, s1);
    // temp_attn
    tattn_kernel<<<100000, 256, 0, stream>>>(efz, s1, dst_idx, W_eattn, b_eattn, tattn);
    // softmax #2 numerator + denominators
    z2s2_kernel<<<1563, 256, 0, stream>>>(ak, aq, src_idx, dst_idx, z2, s2);
    // merge + weighted scatter-aggregation into d_out
    mergeagg_kernel<<<100000, 256, 0, stream>>>(z2, s2, tattn, W_merge, b_merge,
                                                vbuf, src_idx, dst_idx, (float*)d_out);
    // LayerNorm in place
    ln_kernel<<<25000, 256, 0, stream>>>((float*)d_out, ln_gamma, ln_beta);
}

// Round 2
// 1419.424 us; speedup vs baseline: 2.2833x; 2.2833x over previous
//
#include <hip/hip_runtime.h>
#include <math.h>
#include <stdio.h>

#define N_SRC 200000
#define N_DST 100000
#define NE    400000
// IN=128, H=8, D=32, H*D=256

#define SCAN_CHUNK 1024
#define NSCAN ((N_DST + SCAN_CHUNK - 1) / SCAN_CHUNK)   // 98

// ---------------------------------------------------------------------------
// Tiled f32 GEMM: out[n][c] = sum_k A[n][k]*W[c][k] + bias[c] + add_n[n][c] + add_c[c]
// A: [N,K] row-major, W: [C,K] row-major. C multiple of 128.
// Block: 256 threads computes 128 rows x 128 cols. BK=16, 8x8 micro-tile
// in split 4+4 layout (rows ty*4 & 64+ty*4, cols tx*4 & 64+tx*4).
// ---------------------------------------------------------------------------
__global__ __launch_bounds__(256) void gemm128(
    const float* __restrict__ A, const float* __restrict__ W,
    const float* __restrict__ bias, const float* __restrict__ add_n,
    const float* __restrict__ add_c, float* __restrict__ out,
    int N, int K, int C)
{
    __shared__ float As[16][132];   // [k][row]
    __shared__ float Ws[16][132];   // [k][col]

    const int tid = threadIdx.x;
    const int tx  = tid & 15;       // col group
    const int ty  = tid >> 4;       // row group
    const int n0  = blockIdx.y * 128;
    const int c0  = blockIdx.x * 128;

    float acc[8][8];
#pragma unroll
    for (int r = 0; r < 8; ++r)
#pragma unroll
        for (int c = 0; c < 8; ++c) acc[r][c] = 0.f;

    const int a_row = tid >> 1;        // 0..127
    const int a_k8  = (tid & 1) * 8;   // 0 or 8

    for (int k0 = 0; k0 < K; k0 += 16) {
        // ---- load A tile (128 rows x 16 k), 2 float4 per thread ----
        {
            int n = n0 + a_row;
#pragma unroll
            for (int half = 0; half < 2; ++half) {
                int k = k0 + a_k8 + half * 4;
                float4 va = make_float4(0.f, 0.f, 0.f, 0.f);
                if (n < N) {
                    if (k + 3 < K) {
                        va = *(const float4*)&A[(long)n * K + k];
                    } else {
                        float t[4] = {0.f, 0.f, 0.f, 0.f};
                        for (int j = 0; j < 4; ++j) if (k + j < K) t[j] = A[(long)n * K + k + j];
                        va = make_float4(t[0], t[1], t[2], t[3]);
                    }
                }
                As[a_k8 + half * 4 + 0][a_row] = va.x;
                As[a_k8 + half * 4 + 1][a_row] = va.y;
                As[a_k8 + half * 4 + 2][a_row] = va.z;
                As[a_k8 + half * 4 + 3][a_row] = va.w;
            }
        }
        // ---- load W tile (128 cols x 16 k) ----
        {
            int c = c0 + a_row;   // reuse same decomposition
#pragma unroll
            for (int half = 0; half < 2; ++half) {
                int k = k0 + a_k8 + half * 4;
                float4 vw = make_float4(0.f, 0.f, 0.f, 0.f);
                if (k + 3 < K) {
                    vw = *(const float4*)&W[(long)c * K + k];
                } else {
                    float t[4] = {0.f, 0.f, 0.f, 0.f};
                    for (int j = 0; j < 4; ++j) if (k + j < K) t[j] = W[(long)c * K + k + j];
                    vw = make_float4(t[0], t[1], t[2], t[3]);
                }
                Ws[a_k8 + half * 4 + 0][c - c0] = vw.x;
                Ws[a_k8 + half * 4 + 1][c - c0] = vw.y;
                Ws[a_k8 + half * 4 + 2][c - c0] = vw.z;
                Ws[a_k8 + half * 4 + 3][c - c0] = vw.w;
            }
        }
        __syncthreads();
#pragma unroll
        for (int kk = 0; kk < 16; ++kk) {
            float4 a0 = *(const float4*)&As[kk][ty * 4];
            float4 a1 = *(const float4*)&As[kk][64 + ty * 4];
            float4 w0 = *(const float4*)&Ws[kk][tx * 4];
            float4 w1 = *(const float4*)&Ws[kk][64 + tx * 4];
            float av[8] = {a0.x, a0.y, a0.z, a0.w, a1.x, a1.y, a1.z, a1.w};
            float wv[8] = {w0.x, w0.y, w0.z, w0.w, w1.x, w1.y, w1.z, w1.w};
#pragma unroll
            for (int r = 0; r < 8; ++r)
#pragma unroll
                for (int c = 0; c < 8; ++c)
                    acc[r][c] += av[r] * wv[c];
        }
        __syncthreads();
    }

#pragma unroll
    for (int r = 0; r < 8; ++r) {
        int n = n0 + (r < 4 ? ty * 4 + r : 64 + ty * 4 + (r - 4));
        if (n >= N) continue;
#pragma unroll
        for (int cb = 0; cb < 2; ++cb) {
            int cc = c0 + cb * 64 + tx * 4;
            float4 val = make_float4(acc[r][cb * 4 + 0], acc[r][cb * 4 + 1],
                                     acc[r][cb * 4 + 2], acc[r][cb * 4 + 3]);
            if (bias) {
                float4 b = *(const float4*)&bias[cc];
                val.x += b.x; val.y += b.y; val.z += b.z; val.w += b.w;
            }
            if (add_c) {
                float4 b = *(const float4*)&add_c[cc];
                val.x += b.x; val.y += b.y; val.z += b.z; val.w += b.w;
            }
            if (add_n) {
                float4 b = *(const float4*)&add_n[(long)n * C + cc];
                val.x += b.x; val.y += b.y; val.z += b.z; val.w += b.w;
            }
            *(float4*)&out[(long)n * C + cc] = val;
        }
    }
}

// ---------------------------------------------------------------------------
// Fold W_na into Q/K projections: Weff[h][k] = sum_d W[(h*32+d)*128+k]*na[d]
// ---------------------------------------------------------------------------
__global__ void eff_setup(const float* __restrict__ Wq, const float* __restrict__ bq,
                          const float* __restrict__ na_item,
                          const float* __restrict__ Wk, const float* __restrict__ bk,
                          const float* __restrict__ na_user,
                          float* __restrict__ wq_eff, float* __restrict__ bq_eff,
                          float* __restrict__ wk_eff, float* __restrict__ bk_eff)
{
    int tid = threadIdx.x;
    for (int idx = tid; idx < 1024; idx += 256) {
        int h = idx >> 7, k = idx & 127;
        float s1 = 0.f, s2 = 0.f;
        for (int d = 0; d < 32; ++d) {
            s1 += Wq[(h * 32 + d) * 128 + k] * na_item[d];
            s2 += Wk[(h * 32 + d) * 128 + k] * na_user[d];
        }
        wq_eff[idx] = s1;
        wk_eff[idx] = s2;
    }
    if (tid < 8) {
        float s1 = 0.f, s2 = 0.f;
        for (int d = 0; d < 32; ++d) {
            s1 += bq[tid * 32 + d] * na_item[d];
            s2 += bk[tid * 32 + d] * na_user[d];
        }
        bq_eff[tid] = s1;
        bk_eff[tid] = s2;
    }
}

// ---------------------------------------------------------------------------
// Wave-per-row: out[n][h] = sum_k feat[n][k]*weff[h][k] + beff[h], h<8, k<128
// ---------------------------------------------------------------------------
__global__ __launch_bounds__(256) void rowdot8_kernel(
    const float* __restrict__ feat, const float* __restrict__ weff,
    const float* __restrict__ beff, float* __restrict__ out, int N)
{
    int gw   = (blockIdx.x * blockDim.x + threadIdx.x) >> 6;
    int lane = threadIdx.x & 63;
    if (gw >= N) return;
    int c = lane * 2;
    float2 x = *(const float2*)&feat[(long)gw * 128 + c];
    float part[8];
#pragma unroll
    for (int h = 0; h < 8; ++h)
        part[h] = x.x * weff[h * 128 + c] + x.y * weff[h * 128 + c + 1];
#pragma unroll
    for (int h = 0; h < 8; ++h) {
#pragma unroll
        for (int off = 32; off > 0; off >>= 1) part[h] += __shfl_xor(part[h], off);
    }
#pragma unroll
    for (int h = 0; h < 8; ++h)
        if (lane == h) out[(long)gw * 8 + h] = part[h] + beff[h];
}

// ---------------------------------------------------------------------------
// CSR build: histogram -> two-level exclusive scan -> scatter
// ---------------------------------------------------------------------------
__global__ void hist_kernel(const int* __restrict__ dst_idx, int* __restrict__ cnt)
{
    int e = blockIdx.x * blockDim.x + threadIdx.x;
    if (e < NE) atomicAdd(&cnt[dst_idx[e]], 1);
}

__global__ __launch_bounds__(256) void blocksum_kernel(const int* __restrict__ cnt,
                                                       int* __restrict__ bsum)
{
    __shared__ int sm[256];
    int b = blockIdx.x, t = threadIdx.x;
    int s = 0;
    for (int i = t; i < SCAN_CHUNK; i += 256) {
        int idx = b * SCAN_CHUNK + i;
        if (idx < N_DST) s += cnt[idx];
    }
    sm[t] = s; __syncthreads();
    for (int off = 128; off > 0; off >>= 1) {
        if (t < off) sm[t] += sm[t + off];
        __syncthreads();
    }
    if (t == 0) bsum[b] = sm[0];
}

__global__ void scanoff_kernel(const int* __restrict__ bsum, int* __restrict__ boff)
{
    if (threadIdx.x == 0) {
        int r = 0;
        for (int i = 0; i < NSCAN; ++i) { boff[i] = r; r += bsum[i]; }
    }
}

__global__ __launch_bounds__(256) void rowstart_kernel(
    const int* __restrict__ cnt, const int* __restrict__ boff,
    int* __restrict__ row_start, int* __restrict__ cursor)
{
    __shared__ int sm[256];
    int b = blockIdx.x, t = threadIdx.x;
    int base = b * SCAN_CHUNK + t * 4;
    int c[4]; int tot = 0;
#pragma unroll
    for (int j = 0; j < 4; ++j) {
        int idx = base + j;
        c[j] = (idx < N_DST) ? cnt[idx] : 0;
        tot += c[j];
    }
    sm[t] = tot; __syncthreads();
    // Hillis-Steele inclusive scan over 256 thread totals
    for (int off = 1; off < 256; off <<= 1) {
        int v = (t >= off) ? sm[t - off] : 0;
        __syncthreads();
        sm[t] += v;
        __syncthreads();
    }
    int run = sm[t] - tot + boff[b];
#pragma unroll
    for (int j = 0; j < 4; ++j) {
        int idx = base + j;
        if (idx < N_DST) { row_start[idx] = run; cursor[idx] = run; run += c[j]; }
    }
    if (b == 0 && t == 0) row_start[N_DST] = NE;
}

__global__ void scatter_kernel(const int* __restrict__ dst_idx,
                               int* __restrict__ cursor, int* __restrict__ eorder)
{
    int e = blockIdx.x * blockDim.x + threadIdx.x;
    if (e >= NE) return;
    int pos = atomicAdd(&cursor[dst_idx[e]], 1);
    eorder[pos] = e;
}

// ---------------------------------------------------------------------------
// Mega-fused gather: one wave per dst node.
// pass 1: s1[128] (2/lane) and s2[8] (lanes 0..7) in registers
// pass 2: temp_attn + self_attn + merge + v accumulate
// epilogue: LayerNorm, write out.
// ---------------------------------------------------------------------------
__global__ __launch_bounds__(256) void fused_gather_kernel(
    const int* __restrict__ row_start, const int* __restrict__ eorder,
    const int* __restrict__ src_idx,
    const float* __restrict__ ef, const float* __restrict__ src_feat,
    const float* __restrict__ vbuf,
    const float* __restrict__ aq, const float* __restrict__ ak,
    const float* __restrict__ W_eattn, const float* __restrict__ b_eattn,
    const float* __restrict__ W_merge, const float* __restrict__ b_merge,
    const float* __restrict__ ln_gamma, const float* __restrict__ ln_beta,
    float* __restrict__ out)
{
    int gw   = (blockIdx.x * blockDim.x + threadIdx.x) >> 6;
    int lane = threadIdx.x & 63;
    if (gw >= N_DST) return;
    const int dst = gw;
    const int r0 = row_start[dst], r1 = row_start[dst + 1];
    const int ch = lane * 2;
    const int hl = lane & 7;
    const float rsc = 0.17677669529663687f;   // 1/sqrt(32)

    // hoisted loop-invariant weights
    float we0[8], we1[8], be[8], wm[16];
#pragma unroll
    for (int h = 0; h < 8; ++h) {
        we0[h] = W_eattn[h * 128 + ch];
        we1[h] = W_eattn[h * 128 + ch + 1];
        be[h]  = b_eattn[h];
    }
#pragma unroll
    for (int j = 0; j < 16; ++j) wm[j] = W_merge[hl * 16 + j];
    const float bm  = b_merge[hl];
    const float aqh = aq[(long)dst * 8 + hl];

    // ---- pass 1: denominators ----
    float s1x = 0.f, s1y = 0.f, s2l = 0.f;
    for (int j = r0; j < r1; ++j) {
        int eo  = eorder[j];
        int src = src_idx[eo];
        float2 fe = *(const float2*)&ef[(long)eo * 128 + ch];
        float2 fs = *(const float2*)&src_feat[(long)src * 128 + ch];
        s1x += expf(fe.x + fs.x);
        s1y += expf(fe.y + fs.y);
        s2l += expf((ak[(long)src * 8 + hl] + aqh) * rsc);
    }

    // ---- pass 2: attention + aggregate ----
    float ax = 0.f, ay = 0.f, az = 0.f, aw = 0.f;
    for (int j = r0; j < r1; ++j) {
        int eo  = eorder[j];
        int src = src_idx[eo];
        float2 fe = *(const float2*)&ef[(long)eo * 128 + ch];
        float2 fs = *(const float2*)&src_feat[(long)src * 128 + ch];
        float t0 = expf(fe.x + fs.x) / s1x;
        float t1 = expf(fe.y + fs.y) / s1y;
        float part[8];
#pragma unroll
        for (int h = 0; h < 8; ++h) part[h] = t0 * we0[h] + t1 * we1[h];
#pragma unroll
        for (int h = 0; h < 8; ++h) {
#pragma unroll
            for (int off = 32; off > 0; off >>= 1) part[h] += __shfl_xor(part[h], off);
        }
        // self_attn for head hl (valid on lanes 0..7)
        float sa = expf((ak[(long)src * 8 + hl] + aqh) * rsc) / s2l;
        float m = bm;
#pragma unroll
        for (int jj = 0; jj < 8; ++jj) m += wm[jj] * __shfl(sa, jj);
#pragma unroll
        for (int jj = 0; jj < 8; ++jj) m += wm[8 + jj] * (part[jj] + be[jj]);
        float mm = __shfl(m, lane >> 3);   // merged value for this lane's head
        float4 vv = *(const float4*)&vbuf[(long)src * 256 + lane * 4];
        ax += mm * vv.x; ay += mm * vv.y; az += mm * vv.z; aw += mm * vv.w;
    }

    // ---- LayerNorm epilogue ----
    float s = ax + ay + az + aw;
    float q = ax * ax + ay * ay + az * az + aw * aw;
#pragma unroll
    for (int off = 32; off > 0; off >>= 1) {
        s += __shfl_xor(s, off);
        q += __shfl_xor(q, off);
    }
    float mu  = s * (1.0f / 256.0f);
    float var = q * (1.0f / 256.0f) - mu * mu;
    float inv = rsqrtf(var + 1e-5f);
    float4 g = *(const float4*)&ln_gamma[lane * 4];
    float4 b = *(const float4*)&ln_beta[lane * 4];
    float4 o;
    o.x = (ax - mu) * inv * g.x + b.x;
    o.y = (ay - mu) * inv * g.y + b.y;
    o.z = (az - mu) * inv * g.z + b.z;
    o.w = (aw - mu) * inv * g.w + b.w;
    *(float4*)&out[(long)dst * 256 + lane * 4] = o;
}

// ---------------------------------------------------------------------------
extern "C" void kernel_launch(void* const* d_in, const int* in_sizes, int n_in,
                              void* d_out, int out_size, void* d_ws, size_t ws_size,
                              hipStream_t stream)
{
    const float* x_user        = (const float*)d_in[0];
    const float* x_item        = (const float*)d_in[1];
    const float* node_emb_user = (const float*)d_in[2];
    const float* edge_emb      = (const float*)d_in[3];
    const float* edge_feats    = (const float*)d_in[4];
    const int*   src_idx       = (const int*)d_in[5];
    const int*   dst_idx       = (const int*)d_in[6];
    const float* W_nf_user     = (const float*)d_in[7];
    const float* b_nf_user     = (const float*)d_in[8];
    const float* W_nf_item     = (const float*)d_in[9];
    const float* b_nf_item     = (const float*)d_in[10];
    const float* W_ef          = (const float*)d_in[11];
    const float* b_ef          = (const float*)d_in[12];
    const float* W_eattn       = (const float*)d_in[13];
    const float* b_eattn       = (const float*)d_in[14];
    const float* W_merge       = (const float*)d_in[15];
    const float* b_merge       = (const float*)d_in[16];
    const float* W_q           = (const float*)d_in[17];
    const float* b_q           = (const float*)d_in[18];
    const float* W_k           = (const float*)d_in[19];
    const float* b_k           = (const float*)d_in[20];
    const float* W_v           = (const float*)d_in[21];
    const float* b_v           = (const float*)d_in[22];
    const float* W_na_user     = (const float*)d_in[23];
    const float* W_na_item     = (const float*)d_in[24];
    const float* ln_gamma      = (const float*)d_in[25];
    const float* ln_beta       = (const float*)d_in[26];

    float* ws = (float*)d_ws;
    float* src_feat = ws;                        // 25,600,000
    float* dst_feat = src_feat + 25600000;       // 12,800,000
    float* efb      = dst_feat + 12800000;       // 51,200,000
    float* vbuf     = efb + 51200000;            // 51,200,000
    float* aq       = vbuf + 51200000;           //    800,000
    float* ak       = aq + 800000;               //  1,600,000
    float* wq_eff   = ak + 1600000;              //      1,024
    float* wk_eff   = wq_eff + 1024;             //      1,024
    float* bq_eff   = wk_eff + 1024;             //         16
    float* bk_eff   = bq_eff + 16;               //         16
    int*   cnt       = (int*)(bk_eff + 16);      // N_DST
    int*   bsum      = cnt + N_DST;              // 128
    int*   boff      = bsum + 128;               // 128
    int*   row_start = boff + 128;               // N_DST + 1
    int*   cursor    = row_start + N_DST + 1;    // N_DST
    int*   eorder    = cursor + N_DST;           // NE
    size_t needed = (size_t)((char*)(eorder + NE) - (char*)d_ws);
    if (ws_size < needed) {
        fprintf(stderr, "kernel_launch: ws_size %zu < needed %zu\n", ws_size, needed);
        return;
    }

    // zero the histogram (harness does not re-poison between replays)
    hipMemsetAsync(cnt, 0, N_DST * sizeof(int), stream);

    eff_setup<<<1, 256, 0, stream>>>(W_q, b_q, W_na_item, W_k, b_k, W_na_user,
                                     wq_eff, bq_eff, wk_eff, bk_eff);

    // projections
    gemm128<<<dim3(1, 1563), 256, 0, stream>>>(x_user, W_nf_user, b_nf_user,
                                               node_emb_user, edge_emb, src_feat,
                                               N_SRC, 300, 128);
    gemm128<<<dim3(1, 782), 256, 0, stream>>>(x_item, W_nf_item, b_nf_item,
                                              nullptr, edge_emb, dst_feat,
                                              N_DST, 200, 128);
    gemm128<<<dim3(1, 3125), 256, 0, stream>>>(edge_feats, W_ef, b_ef,
                                               nullptr, nullptr, efb,
                                               NE, 64, 128);
    gemm128<<<dim3(2, 1563), 256, 0, stream>>>(src_feat, W_v, b_v,
                                               nullptr, nullptr, vbuf,
                                               N_SRC, 128, 256);
    // aq / ak via folded weights
    rowdot8_kernel<<<25000, 256, 0, stream>>>(dst_feat, wq_eff, bq_eff, aq, N_DST);
    rowdot8_kernel<<<50000, 256, 0, stream>>>(src_feat, wk_eff, bk_eff, ak, N_SRC);

    // CSR build (counting sort by dst)
    hist_kernel<<<1563, 256, 0, stream>>>(dst_idx, cnt);
    blocksum_kernel<<<NSCAN, 256, 0, stream>>>(cnt, bsum);
    scanoff_kernel<<<1, 64, 0, stream>>>(bsum, boff);
    rowstart_kernel<<<NSCAN, 256, 0, stream>>>(cnt, boff, row_start, cursor);
    scatter_kernel<<<1563, 256, 0, stream>>>(dst_idx, cursor, eorder);

    // mega-fused: softmaxes + merge + aggregate + LayerNorm
    fused_gather_kernel<<<25000, 256, 0, stream>>>(
        row_start, eorder, src_idx, efb, src_feat, vbuf, aq, ak,
        W_eattn, b_eattn, W_merge, b_merge, ln_gamma, ln_beta, (float*)d_out);
}

// Round 3
// 976.674 us; speedup vs baseline: 3.3184x; 1.4533x over previous
//
#include <hip/hip_runtime.h>
#include <math.h>
#include <stdio.h>

#define N_SRC 200000
#define N_DST 100000
#define NE    400000
// IN=128, H=8, D=32, H*D=256

#define SCAN_CHUNK 1024
#define NSCAN ((N_DST + SCAN_CHUNK - 1) / SCAN_CHUNK)   // 98

typedef short bf16x8 __attribute__((ext_vector_type(8)));
typedef float f32x4 __attribute__((ext_vector_type(4)));

__device__ __forceinline__ float bflo(unsigned int u) { return __uint_as_float(u << 16); }
__device__ __forceinline__ float bfhi(unsigned int u) { return __uint_as_float(u & 0xFFFF0000u); }
__device__ __forceinline__ unsigned short f2bf(float f) {
    unsigned int u = __float_as_uint(f);
    u += 0x7FFFu + ((u >> 16) & 1u);       // round-to-nearest-even
    return (unsigned short)(u >> 16);
}

// ---------------------------------------------------------------------------
// bf16 MFMA GEMM: out[n][c] = sum_k A[n][k]*W[c][k] (+bias[c]+add_c[c]+add_n[n][c])
// A: f32 [N][K] (ABF=false) or bf16 [N][K] (ABF=true, K%32==0). W: f32 [C][K].
// Outputs: out_lin = bf16(val), out_exp = bf16(exp(val)) (either may be null).
// Block 256 thr = 4 waves; tile 128x128; BK=32; LDS rows padded to 80B
// (conflict-free: each bank hit exactly 2x per wave64 b128 read).
// ---------------------------------------------------------------------------
template<bool ABF>
__global__ __launch_bounds__(256) void gemm_mfma(
    const void* __restrict__ Ap, const float* __restrict__ W,
    const float* __restrict__ bias, const float* __restrict__ add_n,
    const float* __restrict__ add_c,
    unsigned short* __restrict__ out_lin, unsigned short* __restrict__ out_exp,
    int N, int K, int C)
{
    __shared__ __align__(16) unsigned short As[128 * 40];
    __shared__ __align__(16) unsigned short Bs[128 * 40];
    const int tid  = threadIdx.x;
    const int lane = tid & 63;
    const int wv   = tid >> 6;
    const int wr   = wv >> 1, wc = wv & 1;
    const int n0   = blockIdx.y * 128;
    const int c0   = blockIdx.x * 128;
    const int fr   = lane & 15;    // fragment row/col within 16
    const int fq   = lane >> 4;    // k-quarter

    f32x4 acc[4][4];
#pragma unroll
    for (int m = 0; m < 4; ++m)
#pragma unroll
        for (int n = 0; n < 4; ++n) acc[m][n] = (f32x4){0.f, 0.f, 0.f, 0.f};

    const int s_row = tid >> 1;
    const int s_k   = (tid & 1) * 16;
    int arow = n0 + s_row; if (arow >= N) arow = N - 1;
    const int wrow  = c0 + s_row;          // always < C (C multiple of 128)
    const int s_byte = s_row * 80 + s_k * 2;
    const float* Af = (const float*)Ap;
    const unsigned short* Ab = (const unsigned short*)Ap;

    const int KSTEPS = (K + 31) / 32;
    for (int ks = 0; ks < KSTEPS; ++ks) {
        const int kk = ks * 32 + s_k;
        unsigned int ua[8], uw[8];
        if (ABF) {
            uint4 q0 = *(const uint4*)&Ab[(long)arow * K + kk];
            uint4 q1 = *(const uint4*)&Ab[(long)arow * K + kk + 8];
            ua[0] = q0.x; ua[1] = q0.y; ua[2] = q0.z; ua[3] = q0.w;
            ua[4] = q1.x; ua[5] = q1.y; ua[6] = q1.z; ua[7] = q1.w;
        } else {
            float fa[16];
            if (kk + 16 <= K) {
                float4 t0 = *(const float4*)&Af[(long)arow * K + kk];
                float4 t1 = *(const float4*)&Af[(long)arow * K + kk + 4];
                float4 t2 = *(const float4*)&Af[(long)arow * K + kk + 8];
                float4 t3 = *(const float4*)&Af[(long)arow * K + kk + 12];
                fa[0]=t0.x; fa[1]=t0.y; fa[2]=t0.z; fa[3]=t0.w;
                fa[4]=t1.x; fa[5]=t1.y; fa[6]=t1.z; fa[7]=t1.w;
                fa[8]=t2.x; fa[9]=t2.y; fa[10]=t2.z; fa[11]=t2.w;
                fa[12]=t3.x; fa[13]=t3.y; fa[14]=t3.z; fa[15]=t3.w;
            } else {
#pragma unroll
                for (int j = 0; j < 16; ++j) {
                    int k = kk + j;
                    fa[j] = (k < K) ? Af[(long)arow * K + k] : 0.f;
                }
            }
#pragma unroll
            for (int i = 0; i < 8; ++i)
                ua[i] = (unsigned int)f2bf(fa[2*i]) | ((unsigned int)f2bf(fa[2*i+1]) << 16);
        }
        {
            float fw[16];
            if (kk + 16 <= K) {
                float4 t0 = *(const float4*)&W[(long)wrow * K + kk];
                float4 t1 = *(const float4*)&W[(long)wrow * K + kk + 4];
                float4 t2 = *(const float4*)&W[(long)wrow * K + kk + 8];
                float4 t3 = *(const float4*)&W[(long)wrow * K + kk + 12];
                fw[0]=t0.x; fw[1]=t0.y; fw[2]=t0.z; fw[3]=t0.w;
                fw[4]=t1.x; fw[5]=t1.y; fw[6]=t1.z; fw[7]=t1.w;
                fw[8]=t2.x; fw[9]=t2.y; fw[10]=t2.z; fw[11]=t2.w;
                fw[12]=t3.x; fw[13]=t3.y; fw[14]=t3.z; fw[15]=t3.w;
            } else {
#pragma unroll
                for (int j = 0; j < 16; ++j) {
                    int k = kk + j;
                    fw[j] = (k < K) ? W[(long)wrow * K + k] : 0.f;
                }
            }
#pragma unroll
            for (int i = 0; i < 8; ++i)
                uw[i] = (unsigned int)f2bf(fw[2*i]) | ((unsigned int)f2bf(fw[2*i+1]) << 16);
        }
        __syncthreads();
        *(uint4*)((char*)As + s_byte)      = make_uint4(ua[0], ua[1], ua[2], ua[3]);
        *(uint4*)((char*)As + s_byte + 16) = make_uint4(ua[4], ua[5], ua[6], ua[7]);
        *(uint4*)((char*)Bs + s_byte)      = make_uint4(uw[0], uw[1], uw[2], uw[3]);
        *(uint4*)((char*)Bs + s_byte + 16) = make_uint4(uw[4], uw[5], uw[6], uw[7]);
        __syncthreads();
        bf16x8 af[4], bfr[4];
#pragma unroll
        for (int m = 0; m < 4; ++m)
            af[m] = *(const bf16x8*)((const char*)As + (wr*64 + m*16 + fr)*80 + fq*16);
#pragma unroll
        for (int n = 0; n < 4; ++n)
            bfr[n] = *(const bf16x8*)((const char*)Bs + (wc*64 + n*16 + fr)*80 + fq*16);
#pragma unroll
        for (int m = 0; m < 4; ++m)
#pragma unroll
            for (int n = 0; n < 4; ++n)
                acc[m][n] = __builtin_amdgcn_mfma_f32_16x16x32_bf16(af[m], bfr[n], acc[m][n], 0, 0, 0);
    }

    // epilogue: D row = (lane>>4)*4 + reg, col = lane&15 (measured m89/m91)
#pragma unroll
    for (int m = 0; m < 4; ++m) {
#pragma unroll
        for (int j = 0; j < 4; ++j) {
            int row = n0 + wr*64 + m*16 + fq*4 + j;
            if (row >= N) continue;
#pragma unroll
            for (int n = 0; n < 4; ++n) {
                int col = c0 + wc*64 + n*16 + fr;
                float v = acc[m][n][j];
                if (bias)  v += bias[col];
                if (add_c) v += add_c[col];
                if (add_n) v += add_n[(long)row * C + col];
                long o = (long)row * C + col;
                if (out_lin) out_lin[o] = f2bf(v);
                if (out_exp) out_exp[o] = f2bf(expf(v));
            }
        }
    }
}

// ---------------------------------------------------------------------------
// Setup: fold W_na into Q/K (wq_eff/wk_eff [8][128]), fold W_merge x W_eattn
// into Wcomb [8][128], cm[8] = b_merge + W_merge[:,8:] . b_eattn
// ---------------------------------------------------------------------------
__global__ void eff_setup(const float* __restrict__ Wq, const float* __restrict__ bq,
                          const float* __restrict__ na_item,
                          const float* __restrict__ Wk, const float* __restrict__ bk,
                          const float* __restrict__ na_user,
                          const float* __restrict__ W_merge, const float* __restrict__ b_merge,
                          const float* __restrict__ W_eattn, const float* __restrict__ b_eattn,
                          float* __restrict__ wq_eff, float* __restrict__ bq_eff,
                          float* __restrict__ wk_eff, float* __restrict__ bk_eff,
                          float* __restrict__ Wcomb, float* __restrict__ cmv)
{
    int tid = threadIdx.x;
    for (int idx = tid; idx < 1024; idx += 256) {
        int h = idx >> 7, k = idx & 127;
        float s1 = 0.f, s2 = 0.f, s3 = 0.f;
        for (int d = 0; d < 32; ++d) {
            s1 += Wq[(h * 32 + d) * 128 + k] * na_item[d];
            s2 += Wk[(h * 32 + d) * 128 + k] * na_user[d];
        }
        for (int j = 0; j < 8; ++j)
            s3 += W_merge[h * 16 + 8 + j] * W_eattn[j * 128 + k];
        wq_eff[idx] = s1;
        wk_eff[idx] = s2;
        Wcomb[idx]  = s3;
    }
    if (tid < 8) {
        float s1 = 0.f, s2 = 0.f, s3 = b_merge[tid];
        for (int d = 0; d < 32; ++d) {
            s1 += bq[tid * 32 + d] * na_item[d];
            s2 += bk[tid * 32 + d] * na_user[d];
        }
        for (int j = 0; j < 8; ++j) s3 += W_merge[tid * 16 + 8 + j] * b_eattn[j];
        bq_eff[tid] = s1;
        bk_eff[tid] = s2;
        cmv[tid]    = s3;
    }
}

// ---------------------------------------------------------------------------
// Wave-per-row 8-head dot from bf16 features, transpose-butterfly reduce.
// ---------------------------------------------------------------------------
__global__ __launch_bounds__(256) void rowdot8_bf(
    const unsigned short* __restrict__ feat, const float* __restrict__ weff,
    const float* __restrict__ beff, float* __restrict__ out, int N)
{
    int gw   = (blockIdx.x * blockDim.x + threadIdx.x) >> 6;
    int lane = threadIdx.x & 63;
    if (gw >= N) return;
    int ch = lane * 2;
    unsigned int u = *(const unsigned int*)&feat[(long)gw * 128 + ch];
    float x0 = bflo(u), x1 = bfhi(u);
    float part[8];
#pragma unroll
    for (int h = 0; h < 8; ++h)
        part[h] = x0 * weff[h * 128 + ch] + x1 * weff[h * 128 + ch + 1];
    int b0 = lane & 1, b1 = (lane >> 1) & 1, b2 = (lane >> 2) & 1;
    float u0 = (b0 ? part[1] : part[0]) + __shfl_xor(b0 ? part[0] : part[1], 1);
    float u1 = (b0 ? part[3] : part[2]) + __shfl_xor(b0 ? part[2] : part[3], 1);
    float u2 = (b0 ? part[5] : part[4]) + __shfl_xor(b0 ? part[4] : part[5], 1);
    float u3 = (b0 ? part[7] : part[6]) + __shfl_xor(b0 ? part[6] : part[7], 1);
    float w0 = (b1 ? u1 : u0) + __shfl_xor(b1 ? u0 : u1, 2);
    float w1 = (b1 ? u3 : u2) + __shfl_xor(b1 ? u2 : u3, 2);
    float ts = (b2 ? w1 : w0) + __shfl_xor(b2 ? w0 : w1, 4);
    ts += __shfl_xor(ts, 8);
    ts += __shfl_xor(ts, 16);
    ts += __shfl_xor(ts, 32);
    if (lane < 8) out[(long)gw * 8 + lane] = ts + beff[lane];
}

// ---------------------------------------------------------------------------
// CSR build: histogram -> two-level scan -> scatter
// ---------------------------------------------------------------------------
__global__ void hist_kernel(const int* __restrict__ dst_idx, int* __restrict__ cnt)
{
    int e = blockIdx.x * blockDim.x + threadIdx.x;
    if (e < NE) atomicAdd(&cnt[dst_idx[e]], 1);
}

__global__ __launch_bounds__(256) void blocksum_kernel(const int* __restrict__ cnt,
                                                       int* __restrict__ bsum)
{
    __shared__ int sm[256];
    int b = blockIdx.x, t = threadIdx.x;
    int s = 0;
    for (int i = t; i < SCAN_CHUNK; i += 256) {
        int idx = b * SCAN_CHUNK + i;
        if (idx < N_DST) s += cnt[idx];
    }
    sm[t] = s; __syncthreads();
    for (int off = 128; off > 0; off >>= 1) {
        if (t < off) sm[t] += sm[t + off];
        __syncthreads();
    }
    if (t == 0) bsum[b] = sm[0];
}

__global__ void scanoff_kernel(const int* __restrict__ bsum, int* __restrict__ boff)
{
    if (threadIdx.x == 0) {
        int r = 0;
        for (int i = 0; i < NSCAN; ++i) { boff[i] = r; r += bsum[i]; }
    }
}

__global__ __launch_bounds__(256) void rowstart_kernel(
    const int* __restrict__ cnt, const int* __restrict__ boff,
    int* __restrict__ row_start, int* __restrict__ cursor)
{
    __shared__ int sm[256];
    int b = blockIdx.x, t = threadIdx.x;
    int base = b * SCAN_CHUNK + t * 4;
    int c[4]; int tot = 0;
#pragma unroll
    for (int j = 0; j < 4; ++j) {
        int idx = base + j;
        c[j] = (idx < N_DST) ? cnt[idx] : 0;
        tot += c[j];
    }
    sm[t] = tot; __syncthreads();
    for (int off = 1; off < 256; off <<= 1) {
        int v = (t >= off) ? sm[t - off] : 0;
        __syncthreads();
        sm[t] += v;
        __syncthreads();
    }
    int run = sm[t] - tot + boff[b];
#pragma unroll
    for (int j = 0; j < 4; ++j) {
        int idx = base + j;
        if (idx < N_DST) { row_start[idx] = run; cursor[idx] = run; run += c[j]; }
    }
    if (b == 0 && t == 0) row_start[N_DST] = NE;
}

__global__ void scatter_kernel(const int* __restrict__ dst_idx,
                               int* __restrict__ cursor, int* __restrict__ eorder)
{
    int e = blockIdx.x * blockDim.x + threadIdx.x;
    if (e >= NE) return;
    int pos = atomicAdd(&cursor[dst_idx[e]], 1);
    eorder[pos] = e;
}

// ---------------------------------------------------------------------------
// Mega-fused gather v2: one wave per dst. z = P * esf (precomputed exps);
// Wcomb-folded temp path; transpose-butterfly reduce (10 shfl); LN epilogue.
// ---------------------------------------------------------------------------
__global__ __launch_bounds__(256) void fused_gather2(
    const int* __restrict__ row_start, const int* __restrict__ eorder,
    const int* __restrict__ src_idx,
    const unsigned short* __restrict__ Pb, const unsigned short* __restrict__ esfb,
    const unsigned short* __restrict__ vb,
    const float* __restrict__ aq, const float* __restrict__ ak,
    const float* __restrict__ Wcomb, const float* __restrict__ cmv,
    const float* __restrict__ W_merge,
    const float* __restrict__ ln_gamma, const float* __restrict__ ln_beta,
    float* __restrict__ out)
{
    int gw   = (blockIdx.x * blockDim.x + threadIdx.x) >> 6;
    int lane = threadIdx.x & 63;
    if (gw >= N_DST) return;
    const int dst = gw;
    const int r0 = row_start[dst], r1 = row_start[dst + 1];
    const int ch = lane * 2;
    const int hl = lane & 7;
    const int g  = lane >> 3;
    const float rsc = 0.17677669529663687f;   // 1/sqrt(32)

    float wc0[8], wc1[8];
#pragma unroll
    for (int h = 0; h < 8; ++h) {
        wc0[h] = Wcomb[h * 128 + ch];
        wc1[h] = Wcomb[h * 128 + ch + 1];
    }
    const float wself = W_merge[g * 16 + hl];
    const float cmg   = cmv[g];
    const float aqh   = aq[(long)dst * 8 + hl];

    // ---- pass 1: denominators ----
    float s1x = 0.f, s1y = 0.f, s2l = 0.f;
    int eo = 0, src = 0;
    if (r0 < r1) { eo = eorder[r0]; src = src_idx[eo]; }
    for (int j = r0; j < r1; ++j) {
        int eo_n = 0, src_n = 0;
        if (j + 1 < r1) { eo_n = eorder[j + 1]; src_n = src_idx[eo_n]; }
        unsigned int pe = *(const unsigned int*)&Pb[(long)eo * 128 + ch];
        unsigned int se = *(const unsigned int*)&esfb[(long)src * 128 + ch];
        float akh = ak[(long)src * 8 + hl];
        s1x += bflo(pe) * bflo(se);
        s1y += bfhi(pe) * bfhi(se);
        s2l += expf((akh + aqh) * rsc);
        eo = eo_n; src = src_n;
    }
    const float i1x = 1.0f / s1x, i1y = 1.0f / s1y, i2 = 1.0f / s2l;

    // ---- pass 2: attention + aggregate ----
    float ax = 0.f, ay = 0.f, az = 0.f, aw = 0.f;
    if (r0 < r1) { eo = eorder[r0]; src = src_idx[eo]; }
    for (int j = r0; j < r1; ++j) {
        int eo_n = 0, src_n = 0;
        if (j + 1 < r1) { eo_n = eorder[j + 1]; src_n = src_idx[eo_n]; }
        unsigned int pe = *(const unsigned int*)&Pb[(long)eo * 128 + ch];
        unsigned int se = *(const unsigned int*)&esfb[(long)src * 128 + ch];
        float akh = ak[(long)src * 8 + hl];
        uint2 vv = *(const uint2*)&vb[(long)src * 256 + lane * 4];
        float t0 = bflo(pe) * bflo(se) * i1x;
        float t1 = bfhi(pe) * bfhi(se) * i1y;
        float part[8];
#pragma unroll
        for (int h = 0; h < 8; ++h) part[h] = t0 * wc0[h] + t1 * wc1[h];
        // transpose-butterfly: 8 values over 64 lanes in 10 shfl
        int b0 = lane & 1, b1 = (lane >> 1) & 1, b2 = (lane >> 2) & 1;
        float u0 = (b0 ? part[1] : part[0]) + __shfl_xor(b0 ? part[0] : part[1], 1);
        float u1 = (b0 ? part[3] : part[2]) + __shfl_xor(b0 ? part[2] : part[3], 1);
        float u2 = (b0 ? part[5] : part[4]) + __shfl_xor(b0 ? part[4] : part[5], 1);
        float u3 = (b0 ? part[7] : part[6]) + __shfl_xor(b0 ? part[6] : part[7], 1);
        float w0 = (b1 ? u1 : u0) + __shfl_xor(b1 ? u0 : u1, 2);
        float w1 = (b1 ? u3 : u2) + __shfl_xor(b1 ? u2 : u3, 2);
        float ts = (b2 ? w1 : w0) + __shfl_xor(b2 ? w0 : w1, 4);
        ts += __shfl_xor(ts, 8);
        ts += __shfl_xor(ts, 16);
        ts += __shfl_xor(ts, 32);
        // self part: group-local 3-shfl reduce (head g = lane>>3)
        float sa = expf((akh + aqh) * rsc) * i2;
        float ms = wself * sa;
        ms += __shfl_xor(ms, 1);
        ms += __shfl_xor(ms, 2);
        ms += __shfl_xor(ms, 4);
        float mm = cmg + ms + __shfl(ts, g);
        ax += mm * bflo(vv.x); ay += mm * bfhi(vv.x);
        az += mm * bflo(vv.y); aw += mm * bfhi(vv.y);
        eo = eo_n; src = src_n;
    }

    // ---- LayerNorm epilogue ----
    float s = ax + ay + az + aw;
    float q = ax * ax + ay * ay + az * az + aw * aw;
#pragma unroll
    for (int off = 32; off > 0; off >>= 1) {
        s += __shfl_xor(s, off);
        q += __shfl_xor(q, off);
    }
    float mu  = s * (1.0f / 256.0f);
    float var = q * (1.0f / 256.0f) - mu * mu;
    float inv = rsqrtf(var + 1e-5f);
    float4 gg = *(const float4*)&ln_gamma[lane * 4];
    float4 bb = *(const float4*)&ln_beta[lane * 4];
    float4 o;
    o.x = (ax - mu) * inv * gg.x + bb.x;
    o.y = (ay - mu) * inv * gg.y + bb.y;
    o.z = (az - mu) * inv * gg.z + bb.z;
    o.w = (aw - mu) * inv * gg.w + bb.w;
    *(float4*)&out[(long)dst * 256 + lane * 4] = o;
}

// ---------------------------------------------------------------------------
extern "C" void kernel_launch(void* const* d_in, const int* in_sizes, int n_in,
                              void* d_out, int out_size, void* d_ws, size_t ws_size,
                              hipStream_t stream)
{
    const float* x_user        = (const float*)d_in[0];
    const float* x_item        = (const float*)d_in[1];
    const float* node_emb_user = (const float*)d_in[2];
    const float* edge_emb      = (const float*)d_in[3];
    const float* edge_feats    = (const float*)d_in[4];
    const int*   src_idx       = (const int*)d_in[5];
    const int*   dst_idx       = (const int*)d_in[6];
    const float* W_nf_user     = (const float*)d_in[7];
    const float* b_nf_user     = (const float*)d_in[8];
    const float* W_nf_item     = (const float*)d_in[9];
    const float* b_nf_item     = (const float*)d_in[10];
    const float* W_ef          = (const float*)d_in[11];
    const float* b_ef          = (const float*)d_in[12];
    const float* W_eattn       = (const float*)d_in[13];
    const float* b_eattn       = (const float*)d_in[14];
    const float* W_merge       = (const float*)d_in[15];
    const float* b_merge       = (const float*)d_in[16];
    const float* W_q           = (const float*)d_in[17];
    const float* b_q           = (const float*)d_in[18];
    const float* W_k           = (const float*)d_in[19];
    const float* b_k           = (const float*)d_in[20];
    const float* W_v           = (const float*)d_in[21];
    const float* b_v           = (const float*)d_in[22];
    const float* W_na_user     = (const float*)d_in[23];
    const float* W_na_item     = (const float*)d_in[24];
    const float* ln_gamma      = (const float*)d_in[25];
    const float* ln_beta       = (const float*)d_in[26];

    unsigned short* us   = (unsigned short*)d_ws;
    unsigned short* sf_b  = us;                    // 25,600,000  bf16 src_feat
    unsigned short* esf_b = sf_b + 25600000;       // 25,600,000  bf16 exp(src_feat)
    unsigned short* dsf_b = esf_b + 25600000;      // 12,800,000  bf16 dst_feat
    unsigned short* P_b   = dsf_b + 12800000;      // 51,200,000  bf16 exp(ef)
    unsigned short* v_b   = P_b + 51200000;        // 51,200,000  bf16 v
    float* fz     = (float*)(v_b + 51200000);
    float* aq     = fz;                            // 800,000
    float* ak     = aq + 800000;                   // 1,600,000
    float* wq_eff = ak + 1600000;                  // 1024
    float* wk_eff = wq_eff + 1024;                 // 1024
    float* bq_eff = wk_eff + 1024;                 // 16
    float* bk_eff = bq_eff + 16;                   // 16
    float* Wcomb  = bk_eff + 16;                   // 1024
    float* cmv    = Wcomb + 1024;                  // 8
    int*   cnt       = (int*)(cmv + 8);            // N_DST
    int*   bsum      = cnt + N_DST;                // 128
    int*   boff      = bsum + 128;                 // 128
    int*   row_start = boff + 128;                 // N_DST + 1
    int*   cursor    = row_start + N_DST + 1;      // N_DST
    int*   eorder    = cursor + N_DST;             // NE
    size_t needed = (size_t)((char*)(eorder + NE) - (char*)d_ws);
    if (ws_size < needed) {
        fprintf(stderr, "kernel_launch: ws_size %zu < needed %zu\n", ws_size, needed);
        return;
    }

    hipMemsetAsync(cnt, 0, N_DST * sizeof(int), stream);

    eff_setup<<<1, 256, 0, stream>>>(W_q, b_q, W_na_item, W_k, b_k, W_na_user,
                                     W_merge, b_merge, W_eattn, b_eattn,
                                     wq_eff, bq_eff, wk_eff, bk_eff, Wcomb, cmv);

    // GEMM1: src_feat = x_user@W_nf_user^T + b + node_emb + edge_emb -> sf_b & esf_b
    gemm_mfma<false><<<dim3(1, 1563), 256, 0, stream>>>(
        x_user, W_nf_user, b_nf_user, node_emb_user, edge_emb,
        sf_b, esf_b, N_SRC, 300, 128);
    // GEMM2: dst_feat = x_item@W_nf_item^T + b + edge_emb -> dsf_b
    gemm_mfma<false><<<dim3(1, 782), 256, 0, stream>>>(
        x_item, W_nf_item, b_nf_item, nullptr, edge_emb,
        dsf_b, nullptr, N_DST, 200, 128);
    // GEMM3: P = exp(edge_feats@W_ef^T + b_ef) -> P_b
    gemm_mfma<false><<<dim3(1, 3125), 256, 0, stream>>>(
        edge_feats, W_ef, b_ef, nullptr, nullptr,
        nullptr, P_b, NE, 64, 128);
    // GEMM4: v = sf@W_v^T + b_v -> v_b (A is bf16)
    gemm_mfma<true><<<dim3(2, 1563), 256, 0, stream>>>(
        sf_b, W_v, b_v, nullptr, nullptr,
        v_b, nullptr, N_SRC, 128, 256);

    // aq / ak via folded weights
    rowdot8_bf<<<25000, 256, 0, stream>>>(dsf_b, wq_eff, bq_eff, aq, N_DST);
    rowdot8_bf<<<50000, 256, 0, stream>>>(sf_b, wk_eff, bk_eff, ak, N_SRC);

    // CSR build
    hist_kernel<<<1563, 256, 0, stream>>>(dst_idx, cnt);
    blocksum_kernel<<<NSCAN, 256, 0, stream>>>(cnt, bsum);
    scanoff_kernel<<<1, 64, 0, stream>>>(bsum, boff);
    rowstart_kernel<<<NSCAN, 256, 0, stream>>>(cnt, boff, row_start, cursor);
    scatter_kernel<<<1563, 256, 0, stream>>>(dst_idx, cursor, eorder);

    // mega-fused gather + LN
    fused_gather2<<<25000, 256, 0, stream>>>(
        row_start, eorder, src_idx, P_b, esf_b, v_b, aq, ak,
        Wcomb, cmv, W_merge, ln_gamma, ln_beta, (float*)d_out);
}

// Round 4
// 963.170 us; speedup vs baseline: 3.3649x; 1.0140x over previous
//
#include <hip/hip_runtime.h>
#include <math.h>
#include <stdio.h>

#define N_SRC 200000
#define N_DST 100000
#define NE    400000
// IN=128, H=8, D=32, H*D=256

#define SCAN_CHUNK 1024
#define NSCAN ((N_DST + SCAN_CHUNK - 1) / SCAN_CHUNK)   // 98

typedef short bf16x8 __attribute__((ext_vector_type(8)));
typedef float f32x4 __attribute__((ext_vector_type(4)));

__device__ __forceinline__ float bflo(unsigned int u) { return __uint_as_float(u << 16); }
__device__ __forceinline__ float bfhi(unsigned int u) { return __uint_as_float(u & 0xFFFF0000u); }
__device__ __forceinline__ unsigned short f2bf(float f) {
    unsigned int u = __float_as_uint(f);
    u += 0x7FFFu + ((u >> 16) & 1u);       // round-to-nearest-even
    return (unsigned short)(u >> 16);
}

// LDS tile byte offset: 128 rows x 32 bf16 (64B rows), XOR-swizzled so that for
// any fixed 16B chunk index, 8 consecutive rows cover all 8 bank-quad slots.
__device__ __forceinline__ int swz(int row, int chunk) {
    return row * 64 + ((chunk ^ ((row >> 1) & 3)) << 4);
}

// ---------------------------------------------------------------------------
// Pipelined bf16 MFMA GEMM: out[n][c] = sum_k A[n][k]*W[c][k] (+bias+add_c+add_n)
// A: f32 [N][K] (ABF=false) or bf16 [N][K] (ABF=true, K%32==0).
// Wb: bf16 [C][Kp] pre-converted, zero-padded (Kp = ceil(K/32)*32).
// Outputs: out_lin = bf16(val), out_exp = bf16(exp(val)) (either may be null).
// 256 thr = 4 waves; tile 128x128; BK=32; LDS double-buffered (32 KB),
// register prefetch of step k+1 issued before step k's MFMAs; 1 barrier/step.
// ---------------------------------------------------------------------------
template<bool ABF>
__global__ __launch_bounds__(256) void gemm_mfma(
    const void* __restrict__ Ap, const unsigned short* __restrict__ Wb,
    const float* __restrict__ bias, const float* __restrict__ add_n,
    const float* __restrict__ add_c,
    unsigned short* __restrict__ out_lin, unsigned short* __restrict__ out_exp,
    int N, int K, int Kp, int C)
{
    __shared__ __align__(16) unsigned short As[2][128 * 32];
    __shared__ __align__(16) unsigned short Bs[2][128 * 32];
    const int tid  = threadIdx.x;
    const int lane = tid & 63;
    const int wv   = tid >> 6;
    const int wr   = wv >> 1, wc = wv & 1;
    const int n0   = blockIdx.y * 128;
    const int c0   = blockIdx.x * 128;
    const int fr   = lane & 15;
    const int fq   = lane >> 4;

    f32x4 acc[4][4];
#pragma unroll
    for (int m = 0; m < 4; ++m)
#pragma unroll
        for (int n = 0; n < 4; ++n) acc[m][n] = (f32x4){0.f, 0.f, 0.f, 0.f};

    const int s_row = tid >> 1;
    const int h     = tid & 1;
    const int s_k   = h * 16;
    int arow = n0 + s_row; if (arow >= N) arow = N - 1;
    const int wrow  = c0 + s_row;
    const float* Af = (const float*)Ap;
    const unsigned short* Ab = (const unsigned short*)Ap;
    const int KS = (K + 31) / 32;

    const int wb0 = swz(s_row, 2 * h);
    const int wb1 = swz(s_row, 2 * h + 1);

    float4 pa0, pa1, pa2, pa3;   // f32 A prefetch
    uint4  pab0, pab1;           // bf16 A prefetch
    uint4  pw0, pw1;             // bf16 W prefetch

    auto load_step = [&](int ks) {
        const int kk = ks * 32 + s_k;
        if (ABF) {
            pab0 = *(const uint4*)&Ab[(long)arow * K + kk];
            pab1 = *(const uint4*)&Ab[(long)arow * K + kk + 8];
        } else {
            if (kk + 16 <= K) {
                const float* p = &Af[(long)arow * K + kk];
                pa0 = *(const float4*)p;
                pa1 = *(const float4*)(p + 4);
                pa2 = *(const float4*)(p + 8);
                pa3 = *(const float4*)(p + 12);
            } else {
                float t[16];
#pragma unroll
                for (int j = 0; j < 16; ++j) {
                    int k = kk + j;
                    t[j] = (k < K) ? Af[(long)arow * K + k] : 0.f;
                }
                pa0 = make_float4(t[0], t[1], t[2], t[3]);
                pa1 = make_float4(t[4], t[5], t[6], t[7]);
                pa2 = make_float4(t[8], t[9], t[10], t[11]);
                pa3 = make_float4(t[12], t[13], t[14], t[15]);
            }
        }
        pw0 = *(const uint4*)&Wb[(long)wrow * Kp + kk];
        pw1 = *(const uint4*)&Wb[(long)wrow * Kp + kk + 8];
    };

    auto store_step = [&](int buf) {
        uint4 ua0, ua1;
        if (ABF) {
            ua0 = pab0; ua1 = pab1;
        } else {
            ua0.x = (unsigned int)f2bf(pa0.x) | ((unsigned int)f2bf(pa0.y) << 16);
            ua0.y = (unsigned int)f2bf(pa0.z) | ((unsigned int)f2bf(pa0.w) << 16);
            ua0.z = (unsigned int)f2bf(pa1.x) | ((unsigned int)f2bf(pa1.y) << 16);
            ua0.w = (unsigned int)f2bf(pa1.z) | ((unsigned int)f2bf(pa1.w) << 16);
            ua1.x = (unsigned int)f2bf(pa2.x) | ((unsigned int)f2bf(pa2.y) << 16);
            ua1.y = (unsigned int)f2bf(pa2.z) | ((unsigned int)f2bf(pa2.w) << 16);
            ua1.z = (unsigned int)f2bf(pa3.x) | ((unsigned int)f2bf(pa3.y) << 16);
            ua1.w = (unsigned int)f2bf(pa3.z) | ((unsigned int)f2bf(pa3.w) << 16);
        }
        char* ab = (char*)As[buf];
        char* bb = (char*)Bs[buf];
        *(uint4*)(ab + wb0) = ua0;
        *(uint4*)(ab + wb1) = ua1;
        *(uint4*)(bb + wb0) = pw0;
        *(uint4*)(bb + wb1) = pw1;
    };

    load_step(0);
    store_step(0);
    __syncthreads();

    for (int ks = 0; ks < KS; ++ks) {
        if (ks + 1 < KS) load_step(ks + 1);     // prefetch next tile (latency hidden)
        const int buf = ks & 1;
        bf16x8 af[4], bfv[4];
#pragma unroll
        for (int m = 0; m < 4; ++m)
            af[m] = *(const bf16x8*)((const char*)As[buf] + swz(wr * 64 + m * 16 + fr, fq));
#pragma unroll
        for (int n = 0; n < 4; ++n)
            bfv[n] = *(const bf16x8*)((const char*)Bs[buf] + swz(wc * 64 + n * 16 + fr, fq));
#pragma unroll
        for (int m = 0; m < 4; ++m)
#pragma unroll
            for (int n = 0; n < 4; ++n)
                acc[m][n] = __builtin_amdgcn_mfma_f32_16x16x32_bf16(af[m], bfv[n], acc[m][n], 0, 0, 0);
        if (ks + 1 < KS) store_step(buf ^ 1);   // convert + write other buffer
        __syncthreads();
    }

    // epilogue: D row = (lane>>4)*4 + reg, col = lane&15 (measured m89/m91)
#pragma unroll
    for (int m = 0; m < 4; ++m) {
#pragma unroll
        for (int j = 0; j < 4; ++j) {
            int row = n0 + wr * 64 + m * 16 + fq * 4 + j;
            if (row >= N) continue;
#pragma unroll
            for (int n = 0; n < 4; ++n) {
                int col = c0 + wc * 64 + n * 16 + fr;
                float v = acc[m][n][j];
                if (bias)  v += bias[col];
                if (add_c) v += add_c[col];
                if (add_n) v += add_n[(long)row * C + col];
                long o = (long)row * C + col;
                if (out_lin) out_lin[o] = f2bf(v);
                if (out_exp) out_exp[o] = f2bf(expf(v));
            }
        }
    }
}

// ---------------------------------------------------------------------------
// Weight f32 -> bf16 pre-conversion with K padding to Kp (zeros).
// ---------------------------------------------------------------------------
__global__ void wconv(const float* __restrict__ src, unsigned short* __restrict__ dst,
                      int C, int K, int Kp)
{
    int total = C * Kp;
    for (int i = blockIdx.x * blockDim.x + threadIdx.x; i < total; i += gridDim.x * blockDim.x) {
        int c = i / Kp, k = i - c * Kp;
        dst[i] = (k < K) ? f2bf(src[(long)c * K + k]) : (unsigned short)0;
    }
}

// ---------------------------------------------------------------------------
// Setup: fold W_na into Q/K (wq_eff/wk_eff [8][128]), fold W_merge x W_eattn
// into Wcomb [8][128], cm[8] = b_merge + W_merge[:,8:] . b_eattn
// ---------------------------------------------------------------------------
__global__ void eff_setup(const float* __restrict__ Wq, const float* __restrict__ bq,
                          const float* __restrict__ na_item,
                          const float* __restrict__ Wk, const float* __restrict__ bk,
                          const float* __restrict__ na_user,
                          const float* __restrict__ W_merge, const float* __restrict__ b_merge,
                          const float* __restrict__ W_eattn, const float* __restrict__ b_eattn,
                          float* __restrict__ wq_eff, float* __restrict__ bq_eff,
                          float* __restrict__ wk_eff, float* __restrict__ bk_eff,
                          float* __restrict__ Wcomb, float* __restrict__ cmv)
{
    int tid = threadIdx.x;
    for (int idx = tid; idx < 1024; idx += 256) {
        int h = idx >> 7, k = idx & 127;
        float s1 = 0.f, s2 = 0.f, s3 = 0.f;
        for (int d = 0; d < 32; ++d) {
            s1 += Wq[(h * 32 + d) * 128 + k] * na_item[d];
            s2 += Wk[(h * 32 + d) * 128 + k] * na_user[d];
        }
        for (int j = 0; j < 8; ++j)
            s3 += W_merge[h * 16 + 8 + j] * W_eattn[j * 128 + k];
        wq_eff[idx] = s1;
        wk_eff[idx] = s2;
        Wcomb[idx]  = s3;
    }
    if (tid < 8) {
        float s1 = 0.f, s2 = 0.f, s3 = b_merge[tid];
        for (int d = 0; d < 32; ++d) {
            s1 += bq[tid * 32 + d] * na_item[d];
            s2 += bk[tid * 32 + d] * na_user[d];
        }
        for (int j = 0; j < 8; ++j) s3 += W_merge[tid * 16 + 8 + j] * b_eattn[j];
        bq_eff[tid] = s1;
        bk_eff[tid] = s2;
        cmv[tid]    = s3;
    }
}

// ---------------------------------------------------------------------------
// Wave-per-row 8-head dot from bf16 features, transpose-butterfly reduce.
// ---------------------------------------------------------------------------
__global__ __launch_bounds__(256) void rowdot8_bf(
    const unsigned short* __restrict__ feat, const float* __restrict__ weff,
    const float* __restrict__ beff, float* __restrict__ out, int N)
{
    int gw   = (blockIdx.x * blockDim.x + threadIdx.x) >> 6;
    int lane = threadIdx.x & 63;
    if (gw >= N) return;
    int ch = lane * 2;
    unsigned int u = *(const unsigned int*)&feat[(long)gw * 128 + ch];
    float x0 = bflo(u), x1 = bfhi(u);
    float part[8];
#pragma unroll
    for (int h = 0; h < 8; ++h)
        part[h] = x0 * weff[h * 128 + ch] + x1 * weff[h * 128 + ch + 1];
    int b0 = lane & 1, b1 = (lane >> 1) & 1, b2 = (lane >> 2) & 1;
    float u0 = (b0 ? part[1] : part[0]) + __shfl_xor(b0 ? part[0] : part[1], 1);
    float u1 = (b0 ? part[3] : part[2]) + __shfl_xor(b0 ? part[2] : part[3], 1);
    float u2 = (b0 ? part[5] : part[4]) + __shfl_xor(b0 ? part[4] : part[5], 1);
    float u3 = (b0 ? part[7] : part[6]) + __shfl_xor(b0 ? part[6] : part[7], 1);
    float w0 = (b1 ? u1 : u0) + __shfl_xor(b1 ? u0 : u1, 2);
    float w1 = (b1 ? u3 : u2) + __shfl_xor(b1 ? u2 : u3, 2);
    float ts = (b2 ? w1 : w0) + __shfl_xor(b2 ? w0 : w1, 4);
    ts += __shfl_xor(ts, 8);
    ts += __shfl_xor(ts, 16);
    ts += __shfl_xor(ts, 32);
    if (lane < 8) out[(long)gw * 8 + lane] = ts + beff[lane];
}

// ---------------------------------------------------------------------------
// CSR build: histogram -> two-level scan -> scatter
// ---------------------------------------------------------------------------
__global__ void hist_kernel(const int* __restrict__ dst_idx, int* __restrict__ cnt)
{
    int e = blockIdx.x * blockDim.x + threadIdx.x;
    if (e < NE) atomicAdd(&cnt[dst_idx[e]], 1);
}

__global__ __launch_bounds__(256) void blocksum_kernel(const int* __restrict__ cnt,
                                                       int* __restrict__ bsum)
{
    __shared__ int sm[256];
    int b = blockIdx.x, t = threadIdx.x;
    int s = 0;
    for (int i = t; i < SCAN_CHUNK; i += 256) {
        int idx = b * SCAN_CHUNK + i;
        if (idx < N_DST) s += cnt[idx];
    }
    sm[t] = s; __syncthreads();
    for (int off = 128; off > 0; off >>= 1) {
        if (t < off) sm[t] += sm[t + off];
        __syncthreads();
    }
    if (t == 0) bsum[b] = sm[0];
}

__global__ void scanoff_kernel(const int* __restrict__ bsum, int* __restrict__ boff)
{
    if (threadIdx.x == 0) {
        int r = 0;
        for (int i = 0; i < NSCAN; ++i) { boff[i] = r; r += bsum[i]; }
    }
}

__global__ __launch_bounds__(256) void rowstart_kernel(
    const int* __restrict__ cnt, const int* __restrict__ boff,
    int* __restrict__ row_start, int* __restrict__ cursor)
{
    __shared__ int sm[256];
    int b = blockIdx.x, t = threadIdx.x;
    int base = b * SCAN_CHUNK + t * 4;
    int c[4]; int tot = 0;
#pragma unroll
    for (int j = 0; j < 4; ++j) {
        int idx = base + j;
        c[j] = (idx < N_DST) ? cnt[idx] : 0;
        tot += c[j];
    }
    sm[t] = tot; __syncthreads();
    for (int off = 1; off < 256; off <<= 1) {
        int v = (t >= off) ? sm[t - off] : 0;
        __syncthreads();
        sm[t] += v;
        __syncthreads();
    }
    int run = sm[t] - tot + boff[b];
#pragma unroll
    for (int j = 0; j < 4; ++j) {
        int idx = base + j;
        if (idx < N_DST) { row_start[idx] = run; cursor[idx] = run; run += c[j]; }
    }
    if (b == 0 && t == 0) row_start[N_DST] = NE;
}

__global__ void scatter_kernel(const int* __restrict__ dst_idx,
                               int* __restrict__ cursor, int* __restrict__ eorder)
{
    int e = blockIdx.x * blockDim.x + threadIdx.x;
    if (e >= NE) return;
    int pos = atomicAdd(&cursor[dst_idx[e]], 1);
    eorder[pos] = e;
}

// ---------------------------------------------------------------------------
// Mega-fused gather v2: one wave per dst. z = P * esf (precomputed exps);
// Wcomb-folded temp path; transpose-butterfly reduce (10 shfl); LN epilogue.
// ---------------------------------------------------------------------------
__global__ __launch_bounds__(256) void fused_gather2(
    const int* __restrict__ row_start, const int* __restrict__ eorder,
    const int* __restrict__ src_idx,
    const unsigned short* __restrict__ Pb, const unsigned short* __restrict__ esfb,
    const unsigned short* __restrict__ vb,
    const float* __restrict__ aq, const float* __restrict__ ak,
    const float* __restrict__ Wcomb, const float* __restrict__ cmv,
    const float* __restrict__ W_merge,
    const float* __restrict__ ln_gamma, const float* __restrict__ ln_beta,
    float* __restrict__ out)
{
    int gw   = (blockIdx.x * blockDim.x + threadIdx.x) >> 6;
    int lane = threadIdx.x & 63;
    if (gw >= N_DST) return;
    const int dst = gw;
    const int r0 = row_start[dst], r1 = row_start[dst + 1];
    const int ch = lane * 2;
    const int hl = lane & 7;
    const int g  = lane >> 3;
    const float rsc = 0.17677669529663687f;   // 1/sqrt(32)

    float wc0[8], wc1[8];
#pragma unroll
    for (int h = 0; h < 8; ++h) {
        wc0[h] = Wcomb[h * 128 + ch];
        wc1[h] = Wcomb[h * 128 + ch + 1];
    }
    const float wself = W_merge[g * 16 + hl];
    const float cmg   = cmv[g];
    const float aqh   = aq[(long)dst * 8 + hl];

    // ---- pass 1: denominators ----
    float s1x = 0.f, s1y = 0.f, s2l = 0.f;
    int eo = 0, src = 0;
    if (r0 < r1) { eo = eorder[r0]; src = src_idx[eo]; }
    for (int j = r0; j < r1; ++j) {
        int eo_n = 0, src_n = 0;
        if (j + 1 < r1) { eo_n = eorder[j + 1]; src_n = src_idx[eo_n]; }
        unsigned int pe = *(const unsigned int*)&Pb[(long)eo * 128 + ch];
        unsigned int se = *(const unsigned int*)&esfb[(long)src * 128 + ch];
        float akh = ak[(long)src * 8 + hl];
        s1x += bflo(pe) * bflo(se);
        s1y += bfhi(pe) * bfhi(se);
        s2l += expf((akh + aqh) * rsc);
        eo = eo_n; src = src_n;
    }
    const float i1x = 1.0f / s1x, i1y = 1.0f / s1y, i2 = 1.0f / s2l;

    // ---- pass 2: attention + aggregate ----
    float ax = 0.f, ay = 0.f, az = 0.f, aw = 0.f;
    if (r0 < r1) { eo = eorder[r0]; src = src_idx[eo]; }
    for (int j = r0; j < r1; ++j) {
        int eo_n = 0, src_n = 0;
        if (j + 1 < r1) { eo_n = eorder[j + 1]; src_n = src_idx[eo_n]; }
        unsigned int pe = *(const unsigned int*)&Pb[(long)eo * 128 + ch];
        unsigned int se = *(const unsigned int*)&esfb[(long)src * 128 + ch];
        float akh = ak[(long)src * 8 + hl];
        uint2 vv = *(const uint2*)&vb[(long)src * 256 + lane * 4];
        float t0 = bflo(pe) * bflo(se) * i1x;
        float t1 = bfhi(pe) * bfhi(se) * i1y;
        float part[8];
#pragma unroll
        for (int h = 0; h < 8; ++h) part[h] = t0 * wc0[h] + t1 * wc1[h];
        // transpose-butterfly: 8 values over 64 lanes in 10 shfl
        int b0 = lane & 1, b1 = (lane >> 1) & 1, b2 = (lane >> 2) & 1;
        float u0 = (b0 ? part[1] : part[0]) + __shfl_xor(b0 ? part[0] : part[1], 1);
        float u1 = (b0 ? part[3] : part[2]) + __shfl_xor(b0 ? part[2] : part[3], 1);
        float u2 = (b0 ? part[5] : part[4]) + __shfl_xor(b0 ? part[4] : part[5], 1);
        float u3 = (b0 ? part[7] : part[6]) + __shfl_xor(b0 ? part[6] : part[7], 1);
        float w0 = (b1 ? u1 : u0) + __shfl_xor(b1 ? u0 : u1, 2);
        float w1 = (b1 ? u3 : u2) + __shfl_xor(b1 ? u2 : u3, 2);
        float ts = (b2 ? w1 : w0) + __shfl_xor(b2 ? w0 : w1, 4);
        ts += __shfl_xor(ts, 8);
        ts += __shfl_xor(ts, 16);
        ts += __shfl_xor(ts, 32);
        // self part: group-local 3-shfl reduce (head g = lane>>3)
        float sa = expf((akh + aqh) * rsc) * i2;
        float ms = wself * sa;
        ms += __shfl_xor(ms, 1);
        ms += __shfl_xor(ms, 2);
        ms += __shfl_xor(ms, 4);
        float mm = cmg + ms + __shfl(ts, g);
        ax += mm * bflo(vv.x); ay += mm * bfhi(vv.x);
        az += mm * bflo(vv.y); aw += mm * bfhi(vv.y);
        eo = eo_n; src = src_n;
    }

    // ---- LayerNorm epilogue ----
    float s = ax + ay + az + aw;
    float q = ax * ax + ay * ay + az * az + aw * aw;
#pragma unroll
    for (int off = 32; off > 0; off >>= 1) {
        s += __shfl_xor(s, off);
        q += __shfl_xor(q, off);
    }
    float mu  = s * (1.0f / 256.0f);
    float var = q * (1.0f / 256.0f) - mu * mu;
    float inv = rsqrtf(var + 1e-5f);
    float4 gg = *(const float4*)&ln_gamma[lane * 4];
    float4 bb = *(const float4*)&ln_beta[lane * 4];
    float4 o;
    o.x = (ax - mu) * inv * gg.x + bb.x;
    o.y = (ay - mu) * inv * gg.y + bb.y;
    o.z = (az - mu) * inv * gg.z + bb.z;
    o.w = (aw - mu) * inv * gg.w + bb.w;
    *(float4*)&out[(long)dst * 256 + lane * 4] = o;
}

// ---------------------------------------------------------------------------
extern "C" void kernel_launch(void* const* d_in, const int* in_sizes, int n_in,
                              void* d_out, int out_size, void* d_ws, size_t ws_size,
                              hipStream_t stream)
{
    const float* x_user        = (const float*)d_in[0];
    const float* x_item        = (const float*)d_in[1];
    const float* node_emb_user = (const float*)d_in[2];
    const float* edge_emb      = (const float*)d_in[3];
    const float* edge_feats    = (const float*)d_in[4];
    const int*   src_idx       = (const int*)d_in[5];
    const int*   dst_idx       = (const int*)d_in[6];
    const float* W_nf_user     = (const float*)d_in[7];
    const float* b_nf_user     = (const float*)d_in[8];
    const float* W_nf_item     = (const float*)d_in[9];
    const float* b_nf_item     = (const float*)d_in[10];
    const float* W_ef          = (const float*)d_in[11];
    const float* b_ef          = (const float*)d_in[12];
    const float* W_eattn       = (const float*)d_in[13];
    const float* b_eattn       = (const float*)d_in[14];
    const float* W_merge       = (const float*)d_in[15];
    const float* b_merge       = (const float*)d_in[16];
    const float* W_q           = (const float*)d_in[17];
    const float* b_q           = (const float*)d_in[18];
    const float* W_k           = (const float*)d_in[19];
    const float* b_k           = (const float*)d_in[20];
    const float* W_v           = (const float*)d_in[21];
    const float* b_v           = (const float*)d_in[22];
    const float* W_na_user     = (const float*)d_in[23];
    const float* W_na_item     = (const float*)d_in[24];
    const float* ln_gamma      = (const float*)d_in[25];
    const float* ln_beta       = (const float*)d_in[26];

    unsigned short* us   = (unsigned short*)d_ws;
    unsigned short* sf_b  = us;                    // 25,600,000  bf16 src_feat
    unsigned short* esf_b = sf_b + 25600000;       // 25,600,000  bf16 exp(src_feat)
    unsigned short* dsf_b = esf_b + 25600000;      // 12,800,000  bf16 dst_feat
    unsigned short* P_b   = dsf_b + 12800000;      // 51,200,000  bf16 exp(ef)
    unsigned short* v_b   = P_b + 51200000;        // 51,200,000  bf16 v
    float* fz     = (float*)(v_b + 51200000);
    float* aq     = fz;                            // 800,000
    float* ak     = aq + 800000;                   // 1,600,000
    float* wq_eff = ak + 1600000;                  // 1024
    float* wk_eff = wq_eff + 1024;                 // 1024
    float* bq_eff = wk_eff + 1024;                 // 16
    float* bk_eff = bq_eff + 16;                   // 16
    float* Wcomb  = bk_eff + 16;                   // 1024
    float* cmv    = Wcomb + 1024;                  // 8
    int*   cnt       = (int*)(cmv + 8);            // N_DST
    int*   bsum      = cnt + N_DST;                // 128
    int*   boff      = bsum + 128;                 // 128
    int*   row_start = boff + 128;                 // N_DST + 1
    int*   cursor    = row_start + N_DST + 1;      // N_DST
    int*   eorder    = cursor + N_DST;             // NE
    unsigned short* wub = (unsigned short*)(eorder + NE);  // 128*320
    unsigned short* wib = wub + 128 * 320;                 // 128*224
    unsigned short* web = wib + 128 * 224;                 // 128*64
    unsigned short* wvb = web + 128 * 64;                  // 256*128
    size_t needed = (size_t)((char*)(wvb + 256 * 128) - (char*)d_ws);
    if (ws_size < needed) {
        fprintf(stderr, "kernel_launch: ws_size %zu < needed %zu\n", ws_size, needed);
        return;
    }

    hipMemsetAsync(cnt, 0, N_DST * sizeof(int), stream);

    eff_setup<<<1, 256, 0, stream>>>(W_q, b_q, W_na_item, W_k, b_k, W_na_user,
                                     W_merge, b_merge, W_eattn, b_eattn,
                                     wq_eff, bq_eff, wk_eff, bk_eff, Wcomb, cmv);

    // weight pre-conversion to bf16 (padded K)
    wconv<<<64, 256, 0, stream>>>(W_nf_user, wub, 128, 300, 320);
    wconv<<<64, 256, 0, stream>>>(W_nf_item, wib, 128, 200, 224);
    wconv<<<32, 256, 0, stream>>>(W_ef,      web, 128,  64,  64);
    wconv<<<64, 256, 0, stream>>>(W_v,       wvb, 256, 128, 128);

    // GEMM1: src_feat = x_user@W_nf_user^T + b + node_emb + edge_emb -> sf_b & esf_b
    gemm_mfma<false><<<dim3(1, 1563), 256, 0, stream>>>(
        x_user, wub, b_nf_user, node_emb_user, edge_emb,
        sf_b, esf_b, N_SRC, 300, 320, 128);
    // GEMM2: dst_feat = x_item@W_nf_item^T + b + edge_emb -> dsf_b
    gemm_mfma<false><<<dim3(1, 782), 256, 0, stream>>>(
        x_item, wib, b_nf_item, nullptr, edge_emb,
        dsf_b, nullptr, N_DST, 200, 224, 128);
    // GEMM3: P = exp(edge_feats@W_ef^T + b_ef) -> P_b
    gemm_mfma<false><<<dim3(1, 3125), 256, 0, stream>>>(
        edge_feats, web, b_ef, nullptr, nullptr,
        nullptr, P_b, NE, 64, 64, 128);
    // GEMM4: v = sf@W_v^T + b_v -> v_b (A is bf16)
    gemm_mfma<true><<<dim3(2, 1563), 256, 0, stream>>>(
        sf_b, wvb, b_v, nullptr, nullptr,
        v_b, nullptr, N_SRC, 128, 128, 256);

    // aq / ak via folded weights
    rowdot8_bf<<<25000, 256, 0, stream>>>(dsf_b, wq_eff, bq_eff, aq, N_DST);
    rowdot8_bf<<<50000, 256, 0, stream>>>(sf_b, wk_eff, bk_eff, ak, N_SRC);

    // CSR build
    hist_kernel<<<1563, 256, 0, stream>>>(dst_idx, cnt);
    blocksum_kernel<<<NSCAN, 256, 0, stream>>>(cnt, bsum);
    scanoff_kernel<<<1, 64, 0, stream>>>(bsum, boff);
    rowstart_kernel<<<NSCAN, 256, 0, stream>>>(cnt, boff, row_start, cursor);
    scatter_kernel<<<1563, 256, 0, stream>>>(dst_idx, cursor, eorder);

    // mega-fused gather + LN
    fused_gather2<<<25000, 256, 0, stream>>>(
        row_start, eorder, src_idx, P_b, esf_b, v_b, aq, ak,
        Wcomb, cmv, W_merge, ln_gamma, ln_beta, (float*)d_out);
}

// Round 5
// 872.547 us; speedup vs baseline: 3.7144x; 1.1039x over previous
//
#include <hip/hip_runtime.h>
#include <math.h>
#include <stdio.h>
#include <stdint.h>

#define N_SRC 200000
#define N_DST 100000
#define NE    400000
// IN=128, H=8, D=32, H*D=256

#define SCAN_CHUNK 1024
#define NSCAN ((N_DST + SCAN_CHUNK - 1) / SCAN_CHUNK)   // 98

typedef short bf16x8 __attribute__((ext_vector_type(8)));
typedef float f32x4 __attribute__((ext_vector_type(4)));

__device__ __forceinline__ float bflo(unsigned int u) { return __uint_as_float(u << 16); }
__device__ __forceinline__ float bfhi(unsigned int u) { return __uint_as_float(u & 0xFFFF0000u); }
__device__ __forceinline__ unsigned short f2bf(float f) {
    unsigned int u = __float_as_uint(f);
    u += 0x7FFFu + ((u >> 16) & 1u);       // round-to-nearest-even
    return (unsigned short)(u >> 16);
}

// ---------------------------------------------------------------------------
// Barrier-free streaming MFMA GEMM.  out[n][c] = sum_k A[n][k]*W[c][k]
// (+bias[c]+add_c[c]+add_n[n][c]).  NO LDS, NO barriers:
//  - each wave owns 32 rows (2 m-tiles) x all C cols (NT n-tiles);
//    A-fragments load global->reg (rows are wave-private => A read once).
//  - W pre-converted to B-fragment layout (wconv_frag): one coalesced
//    dwordx4 per fragment, L2-resident (<=80KB), shared by all blocks.
//  - depth-1 register prefetch of A and B; waves run fully decoupled.
// A: f32 [N][K] (ABF=false) or bf16 [N][K] (ABF=true, K%32==0).
// ---------------------------------------------------------------------------
template<bool ABF, int NT>
__global__ __launch_bounds__(256) void gemm_stream(
    const void* __restrict__ Ap, const unsigned short* __restrict__ Wf,
    const float* __restrict__ bias, const float* __restrict__ add_n,
    const float* __restrict__ add_c,
    unsigned short* __restrict__ out_lin, unsigned short* __restrict__ out_exp,
    int N, int K, int KS, int C)
{
    const int tid  = threadIdx.x;
    const int lane = tid & 63;
    const int wv   = tid >> 6;
    const int fr   = lane & 15;
    const int fq   = lane >> 4;
    const int row0 = blockIdx.y * 128 + wv * 32;

    long ar[2];
    {
        int r0 = row0 + fr;       if (r0 >= N) r0 = N - 1;
        int r1 = row0 + 16 + fr;  if (r1 >= N) r1 = N - 1;
        ar[0] = (long)r0 * K;
        ar[1] = (long)r1 * K;
    }
    const float* Af = (const float*)Ap;
    const unsigned short* Ab = (const unsigned short*)Ap;

    f32x4 acc[2][NT];
#pragma unroll
    for (int m = 0; m < 2; ++m)
#pragma unroll
        for (int n = 0; n < NT; ++n) acc[m][n] = (f32x4){0.f, 0.f, 0.f, 0.f};

    float4 pa[2][2];   // f32 A prefetch
    uint4  pab[2];     // bf16 A prefetch
    uint4  pb[NT];     // B-fragment prefetch

    auto loadA = [&](int ks) {
        const int kk = ks * 32 + fq * 8;
        if (ABF) {
#pragma unroll
            for (int m = 0; m < 2; ++m)
                pab[m] = *(const uint4*)&Ab[ar[m] + kk];
        } else {
            if (kk + 8 <= K) {
#pragma unroll
                for (int m = 0; m < 2; ++m) {
                    const float* p = &Af[ar[m] + kk];
                    pa[m][0] = *(const float4*)p;
                    pa[m][1] = *(const float4*)(p + 4);
                }
            } else {
#pragma unroll
                for (int m = 0; m < 2; ++m) {
                    float t[8];
#pragma unroll
                    for (int j = 0; j < 8; ++j)
                        t[j] = (kk + j < K) ? Af[ar[m] + kk + j] : 0.f;
                    pa[m][0] = make_float4(t[0], t[1], t[2], t[3]);
                    pa[m][1] = make_float4(t[4], t[5], t[6], t[7]);
                }
            }
        }
    };
    auto loadB = [&](int ks) {
#pragma unroll
        for (int n = 0; n < NT; ++n)
            pb[n] = *(const uint4*)&Wf[(size_t)(((n * KS + ks) << 6) | lane) << 3];
    };

    loadA(0);
    loadB(0);
    for (int ks = 0; ks < KS; ++ks) {
        bf16x8 ca[2], cb[NT];
        if (ABF) {
#pragma unroll
            for (int m = 0; m < 2; ++m) ca[m] = *(bf16x8*)&pab[m];
        } else {
#pragma unroll
            for (int m = 0; m < 2; ++m) {
                uint4 u;
                u.x = (unsigned)f2bf(pa[m][0].x) | ((unsigned)f2bf(pa[m][0].y) << 16);
                u.y = (unsigned)f2bf(pa[m][0].z) | ((unsigned)f2bf(pa[m][0].w) << 16);
                u.z = (unsigned)f2bf(pa[m][1].x) | ((unsigned)f2bf(pa[m][1].y) << 16);
                u.w = (unsigned)f2bf(pa[m][1].z) | ((unsigned)f2bf(pa[m][1].w) << 16);
                ca[m] = *(bf16x8*)&u;
            }
        }
#pragma unroll
        for (int n = 0; n < NT; ++n) cb[n] = *(bf16x8*)&pb[n];
        if (ks + 1 < KS) { loadA(ks + 1); loadB(ks + 1); }
#pragma unroll
        for (int m = 0; m < 2; ++m)
#pragma unroll
            for (int n = 0; n < NT; ++n)
                acc[m][n] = __builtin_amdgcn_mfma_f32_16x16x32_bf16(ca[m], cb[n], acc[m][n], 0, 0, 0);
    }

    // epilogue: D col = lane&15, row = (lane>>4)*4 + reg (measured m89/m91)
    float bc[NT];
#pragma unroll
    for (int n = 0; n < NT; ++n) {
        int col = n * 16 + fr;
        float b = 0.f;
        if (bias)  b += bias[col];
        if (add_c) b += add_c[col];
        bc[n] = b;
    }
#pragma unroll
    for (int m = 0; m < 2; ++m) {
#pragma unroll
        for (int j = 0; j < 4; ++j) {
            int row = row0 + m * 16 + fq * 4 + j;
            if (row >= N) continue;
#pragma unroll
            for (int n = 0; n < NT; ++n) {
                int col = n * 16 + fr;
                float v = acc[m][n][j] + bc[n];
                if (add_n) v += add_n[(long)row * C + col];
                long o = (long)row * C + col;
                if (out_lin) out_lin[o] = f2bf(v);
                if (out_exp) out_exp[o] = f2bf(expf(v));
            }
        }
    }
}

// ---------------------------------------------------------------------------
// Weight f32 [C][K] -> bf16 B-fragment layout, zero-padded to Kp (KS=Kp/32):
// dst[((n*KS+ks)*64+l)*8 + j] = W[n*16 + (l&15)][ks*32 + (l>>4)*8 + j]
// ---------------------------------------------------------------------------
__global__ void wconv_frag(const float* __restrict__ src, unsigned short* __restrict__ dst,
                           int C, int K, int Kp)
{
    int KS = Kp >> 5;
    int total = C * Kp;
    for (int i = blockIdx.x * blockDim.x + threadIdx.x; i < total; i += gridDim.x * blockDim.x) {
        int j  = i & 7;
        int l  = (i >> 3) & 63;
        int t  = i >> 9;
        int ks = t % KS;
        int n  = t / KS;
        int col = n * 16 + (l & 15);
        int k   = ks * 32 + ((l >> 4) << 3) + j;
        dst[i] = (k < K) ? f2bf(src[(long)col * K + k]) : (unsigned short)0;
    }
}

// ---------------------------------------------------------------------------
// Setup: fold W_na into Q/K (wq_eff/wk_eff [8][128]), fold W_merge x W_eattn
// into Wcomb [8][128], cm[8] = b_merge + W_merge[:,8:] . b_eattn
// ---------------------------------------------------------------------------
__global__ void eff_setup(const float* __restrict__ Wq, const float* __restrict__ bq,
                          const float* __restrict__ na_item,
                          const float* __restrict__ Wk, const float* __restrict__ bk,
                          const float* __restrict__ na_user,
                          const float* __restrict__ W_merge, const float* __restrict__ b_merge,
                          const float* __restrict__ W_eattn, const float* __restrict__ b_eattn,
                          float* __restrict__ wq_eff, float* __restrict__ bq_eff,
                          float* __restrict__ wk_eff, float* __restrict__ bk_eff,
                          float* __restrict__ Wcomb, float* __restrict__ cmv)
{
    int tid = threadIdx.x;
    for (int idx = tid; idx < 1024; idx += 256) {
        int h = idx >> 7, k = idx & 127;
        float s1 = 0.f, s2 = 0.f, s3 = 0.f;
        for (int d = 0; d < 32; ++d) {
            s1 += Wq[(h * 32 + d) * 128 + k] * na_item[d];
            s2 += Wk[(h * 32 + d) * 128 + k] * na_user[d];
        }
        for (int j = 0; j < 8; ++j)
            s3 += W_merge[h * 16 + 8 + j] * W_eattn[j * 128 + k];
        wq_eff[idx] = s1;
        wk_eff[idx] = s2;
        Wcomb[idx]  = s3;
    }
    if (tid < 8) {
        float s1 = 0.f, s2 = 0.f, s3 = b_merge[tid];
        for (int d = 0; d < 32; ++d) {
            s1 += bq[tid * 32 + d] * na_item[d];
            s2 += bk[tid * 32 + d] * na_user[d];
        }
        for (int j = 0; j < 8; ++j) s3 += W_merge[tid * 16 + 8 + j] * b_eattn[j];
        bq_eff[tid] = s1;
        bk_eff[tid] = s2;
        cmv[tid]    = s3;
    }
}

// ---------------------------------------------------------------------------
// Wave-per-row 8-head dot from bf16 features, transpose-butterfly reduce.
// ---------------------------------------------------------------------------
__global__ __launch_bounds__(256) void rowdot8_bf(
    const unsigned short* __restrict__ feat, const float* __restrict__ weff,
    const float* __restrict__ beff, float* __restrict__ out, int N)
{
    int gw   = (blockIdx.x * blockDim.x + threadIdx.x) >> 6;
    int lane = threadIdx.x & 63;
    if (gw >= N) return;
    int ch = lane * 2;
    unsigned int u = *(const unsigned int*)&feat[(long)gw * 128 + ch];
    float x0 = bflo(u), x1 = bfhi(u);
    float part[8];
#pragma unroll
    for (int h = 0; h < 8; ++h)
        part[h] = x0 * weff[h * 128 + ch] + x1 * weff[h * 128 + ch + 1];
    int b0 = lane & 1, b1 = (lane >> 1) & 1, b2 = (lane >> 2) & 1;
    float u0 = (b0 ? part[1] : part[0]) + __shfl_xor(b0 ? part[0] : part[1], 1);
    float u1 = (b0 ? part[3] : part[2]) + __shfl_xor(b0 ? part[2] : part[3], 1);
    float u2 = (b0 ? part[5] : part[4]) + __shfl_xor(b0 ? part[4] : part[5], 1);
    float u3 = (b0 ? part[7] : part[6]) + __shfl_xor(b0 ? part[6] : part[7], 1);
    float w0 = (b1 ? u1 : u0) + __shfl_xor(b1 ? u0 : u1, 2);
    float w1 = (b1 ? u3 : u2) + __shfl_xor(b1 ? u2 : u3, 2);
    float ts = (b2 ? w1 : w0) + __shfl_xor(b2 ? w0 : w1, 4);
    ts += __shfl_xor(ts, 8);
    ts += __shfl_xor(ts, 16);
    ts += __shfl_xor(ts, 32);
    if (lane < 8) out[(long)gw * 8 + lane] = ts + beff[lane];
}

// ---------------------------------------------------------------------------
// CSR build: histogram -> two-level scan -> scatter
// ---------------------------------------------------------------------------
__global__ void hist_kernel(const int* __restrict__ dst_idx, int* __restrict__ cnt)
{
    int e = blockIdx.x * blockDim.x + threadIdx.x;
    if (e < NE) atomicAdd(&cnt[dst_idx[e]], 1);
}

__global__ __launch_bounds__(256) void blocksum_kernel(const int* __restrict__ cnt,
                                                       int* __restrict__ bsum)
{
    __shared__ int sm[256];
    int b = blockIdx.x, t = threadIdx.x;
    int s = 0;
    for (int i = t; i < SCAN_CHUNK; i += 256) {
        int idx = b * SCAN_CHUNK + i;
        if (idx < N_DST) s += cnt[idx];
    }
    sm[t] = s; __syncthreads();
    for (int off = 128; off > 0; off >>= 1) {
        if (t < off) sm[t] += sm[t + off];
        __syncthreads();
    }
    if (t == 0) bsum[b] = sm[0];
}

__global__ void scanoff_kernel(const int* __restrict__ bsum, int* __restrict__ boff)
{
    if (threadIdx.x == 0) {
        int r = 0;
        for (int i = 0; i < NSCAN; ++i) { boff[i] = r; r += bsum[i]; }
    }
}

__global__ __launch_bounds__(256) void rowstart_kernel(
    const int* __restrict__ cnt, const int* __restrict__ boff,
    int* __restrict__ row_start, int* __restrict__ cursor)
{
    __shared__ int sm[256];
    int b = blockIdx.x, t = threadIdx.x;
    int base = b * SCAN_CHUNK + t * 4;
    int c[4]; int tot = 0;
#pragma unroll
    for (int j = 0; j < 4; ++j) {
        int idx = base + j;
        c[j] = (idx < N_DST) ? cnt[idx] : 0;
        tot += c[j];
    }
    sm[t] = tot; __syncthreads();
    for (int off = 1; off < 256; off <<= 1) {
        int v = (t >= off) ? sm[t - off] : 0;
        __syncthreads();
        sm[t] += v;
        __syncthreads();
    }
    int run = sm[t] - tot + boff[b];
#pragma unroll
    for (int j = 0; j < 4; ++j) {
        int idx = base + j;
        if (idx < N_DST) { row_start[idx] = run; cursor[idx] = run; run += c[j]; }
    }
    if (b == 0 && t == 0) row_start[N_DST] = NE;
}

__global__ void scatter_kernel(const int* __restrict__ dst_idx,
                               int* __restrict__ cursor, int* __restrict__ eorder)
{
    int e = blockIdx.x * blockDim.x + threadIdx.x;
    if (e >= NE) return;
    int pos = atomicAdd(&cursor[dst_idx[e]], 1);
    eorder[pos] = e;
}

// ---------------------------------------------------------------------------
// Mega-fused gather v2: one wave per dst. z = P * esf (precomputed exps);
// Wcomb-folded temp path; transpose-butterfly reduce (10 shfl); LN epilogue.
// ---------------------------------------------------------------------------
__global__ __launch_bounds__(256) void fused_gather2(
    const int* __restrict__ row_start, const int* __restrict__ eorder,
    const int* __restrict__ src_idx,
    const unsigned short* __restrict__ Pb, const unsigned short* __restrict__ esfb,
    const unsigned short* __restrict__ vb,
    const float* __restrict__ aq, const float* __restrict__ ak,
    const float* __restrict__ Wcomb, const float* __restrict__ cmv,
    const float* __restrict__ W_merge,
    const float* __restrict__ ln_gamma, const float* __restrict__ ln_beta,
    float* __restrict__ out)
{
    int gw   = (blockIdx.x * blockDim.x + threadIdx.x) >> 6;
    int lane = threadIdx.x & 63;
    if (gw >= N_DST) return;
    const int dst = gw;
    const int r0 = row_start[dst], r1 = row_start[dst + 1];
    const int ch = lane * 2;
    const int hl = lane & 7;
    const int g  = lane >> 3;
    const float rsc = 0.17677669529663687f;   // 1/sqrt(32)

    float wc0[8], wc1[8];
#pragma unroll
    for (int h = 0; h < 8; ++h) {
        wc0[h] = Wcomb[h * 128 + ch];
        wc1[h] = Wcomb[h * 128 + ch + 1];
    }
    const float wself = W_merge[g * 16 + hl];
    const float cmg   = cmv[g];
    const float aqh   = aq[(long)dst * 8 + hl];

    // ---- pass 1: denominators ----
    float s1x = 0.f, s1y = 0.f, s2l = 0.f;
    int eo = 0, src = 0;
    if (r0 < r1) { eo = eorder[r0]; src = src_idx[eo]; }
    for (int j = r0; j < r1; ++j) {
        int eo_n = 0, src_n = 0;
        if (j + 1 < r1) { eo_n = eorder[j + 1]; src_n = src_idx[eo_n]; }
        unsigned int pe = *(const unsigned int*)&Pb[(long)eo * 128 + ch];
        unsigned int se = *(const unsigned int*)&esfb[(long)src * 128 + ch];
        float akh = ak[(long)src * 8 + hl];
        s1x += bflo(pe) * bflo(se);
        s1y += bfhi(pe) * bfhi(se);
        s2l += expf((akh + aqh) * rsc);
        eo = eo_n; src = src_n;
    }
    const float i1x = 1.0f / s1x, i1y = 1.0f / s1y, i2 = 1.0f / s2l;

    // ---- pass 2: attention + aggregate ----
    float ax = 0.f, ay = 0.f, az = 0.f, aw = 0.f;
    if (r0 < r1) { eo = eorder[r0]; src = src_idx[eo]; }
    for (int j = r0; j < r1; ++j) {
        int eo_n = 0, src_n = 0;
        if (j + 1 < r1) { eo_n = eorder[j + 1]; src_n = src_idx[eo_n]; }
        unsigned int pe = *(const unsigned int*)&Pb[(long)eo * 128 + ch];
        unsigned int se = *(const unsigned int*)&esfb[(long)src * 128 + ch];
        float akh = ak[(long)src * 8 + hl];
        uint2 vv = *(const uint2*)&vb[(long)src * 256 + lane * 4];
        float t0 = bflo(pe) * bflo(se) * i1x;
        float t1 = bfhi(pe) * bfhi(se) * i1y;
        float part[8];
#pragma unroll
        for (int h = 0; h < 8; ++h) part[h] = t0 * wc0[h] + t1 * wc1[h];
        // transpose-butterfly: 8 values over 64 lanes in 10 shfl
        int b0 = lane & 1, b1 = (lane >> 1) & 1, b2 = (lane >> 2) & 1;
        float u0 = (b0 ? part[1] : part[0]) + __shfl_xor(b0 ? part[0] : part[1], 1);
        float u1 = (b0 ? part[3] : part[2]) + __shfl_xor(b0 ? part[2] : part[3], 1);
        float u2 = (b0 ? part[5] : part[4]) + __shfl_xor(b0 ? part[4] : part[5], 1);
        float u3 = (b0 ? part[7] : part[6]) + __shfl_xor(b0 ? part[6] : part[7], 1);
        float w0 = (b1 ? u1 : u0) + __shfl_xor(b1 ? u0 : u1, 2);
        float w1 = (b1 ? u3 : u2) + __shfl_xor(b1 ? u2 : u3, 2);
        float ts = (b2 ? w1 : w0) + __shfl_xor(b2 ? w0 : w1, 4);
        ts += __shfl_xor(ts, 8);
        ts += __shfl_xor(ts, 16);
        ts += __shfl_xor(ts, 32);
        // self part: group-local 3-shfl reduce (head g = lane>>3)
        float sa = expf((akh + aqh) * rsc) * i2;
        float ms = wself * sa;
        ms += __shfl_xor(ms, 1);
        ms += __shfl_xor(ms, 2);
        ms += __shfl_xor(ms, 4);
        float mm = cmg + ms + __shfl(ts, g);
        ax += mm * bflo(vv.x); ay += mm * bfhi(vv.x);
        az += mm * bflo(vv.y); aw += mm * bfhi(vv.y);
        eo = eo_n; src = src_n;
    }

    // ---- LayerNorm epilogue ----
    float s = ax + ay + az + aw;
    float q = ax * ax + ay * ay + az * az + aw * aw;
#pragma unroll
    for (int off = 32; off > 0; off >>= 1) {
        s += __shfl_xor(s, off);
        q += __shfl_xor(q, off);
    }
    float mu  = s * (1.0f / 256.0f);
    float var = q * (1.0f / 256.0f) - mu * mu;
    float inv = rsqrtf(var + 1e-5f);
    float4 gg = *(const float4*)&ln_gamma[lane * 4];
    float4 bb = *(const float4*)&ln_beta[lane * 4];
    float4 o;
    o.x = (ax - mu) * inv * gg.x + bb.x;
    o.y = (ay - mu) * inv * gg.y + bb.y;
    o.z = (az - mu) * inv * gg.z + bb.z;
    o.w = (aw - mu) * inv * gg.w + bb.w;
    *(float4*)&out[(long)dst * 256 + lane * 4] = o;
}

// ---------------------------------------------------------------------------
extern "C" void kernel_launch(void* const* d_in, const int* in_sizes, int n_in,
                              void* d_out, int out_size, void* d_ws, size_t ws_size,
                              hipStream_t stream)
{
    const float* x_user        = (const float*)d_in[0];
    const float* x_item        = (const float*)d_in[1];
    const float* node_emb_user = (const float*)d_in[2];
    const float* edge_emb      = (const float*)d_in[3];
    const float* edge_feats    = (const float*)d_in[4];
    const int*   src_idx       = (const int*)d_in[5];
    const int*   dst_idx       = (const int*)d_in[6];
    const float* W_nf_user     = (const float*)d_in[7];
    const float* b_nf_user     = (const float*)d_in[8];
    const float* W_nf_item     = (const float*)d_in[9];
    const float* b_nf_item     = (const float*)d_in[10];
    const float* W_ef          = (const float*)d_in[11];
    const float* b_ef          = (const float*)d_in[12];
    const float* W_eattn       = (const float*)d_in[13];
    const float* b_eattn       = (const float*)d_in[14];
    const float* W_merge       = (const float*)d_in[15];
    const float* b_merge       = (const float*)d_in[16];
    const float* W_q           = (const float*)d_in[17];
    const float* b_q           = (const float*)d_in[18];
    const float* W_k           = (const float*)d_in[19];
    const float* b_k           = (const float*)d_in[20];
    const float* W_v           = (const float*)d_in[21];
    const float* b_v           = (const float*)d_in[22];
    const float* W_na_user     = (const float*)d_in[23];
    const float* W_na_item     = (const float*)d_in[24];
    const float* ln_gamma      = (const float*)d_in[25];
    const float* ln_beta       = (const float*)d_in[26];

    unsigned short* us   = (unsigned short*)d_ws;
    unsigned short* sf_b  = us;                    // 25,600,000  bf16 src_feat
    unsigned short* esf_b = sf_b + 25600000;       // 25,600,000  bf16 exp(src_feat)
    unsigned short* dsf_b = esf_b + 25600000;      // 12,800,000  bf16 dst_feat
    unsigned short* P_b   = dsf_b + 12800000;      // 51,200,000  bf16 exp(ef)
    unsigned short* v_b   = P_b + 51200000;        // 51,200,000  bf16 v
    float* fz     = (float*)(v_b + 51200000);
    float* aq     = fz;                            // 800,000
    float* ak     = aq + 800000;                   // 1,600,000
    float* wq_eff = ak + 1600000;                  // 1024
    float* wk_eff = wq_eff + 1024;                 // 1024
    float* bq_eff = wk_eff + 1024;                 // 16
    float* bk_eff = bq_eff + 16;                   // 16
    float* Wcomb  = bk_eff + 16;                   // 1024
    float* cmv    = Wcomb + 1024;                  // 8
    int*   cnt       = (int*)(cmv + 8);            // N_DST
    int*   bsum      = cnt + N_DST;                // 128
    int*   boff      = bsum + 128;                 // 128
    int*   row_start = boff + 128;                 // N_DST + 1
    int*   cursor    = row_start + N_DST + 1;      // N_DST
    int*   eorder    = cursor + N_DST;             // NE
    // W fragment buffers (16B-aligned for dwordx4 loads)
    unsigned short* wub = (unsigned short*)(((uintptr_t)(eorder + NE) + 15) & ~(uintptr_t)15);
    unsigned short* wib = wub + 128 * 320;                 // 128*224
    unsigned short* web = wib + 128 * 224;                 // 128*64
    unsigned short* wvb = web + 128 * 64;                  // 256*128
    size_t needed = (size_t)((char*)(wvb + 256 * 128) - (char*)d_ws);
    if (ws_size < needed) {
        fprintf(stderr, "kernel_launch: ws_size %zu < needed %zu\n", ws_size, needed);
        return;
    }

    hipMemsetAsync(cnt, 0, N_DST * sizeof(int), stream);

    eff_setup<<<1, 256, 0, stream>>>(W_q, b_q, W_na_item, W_k, b_k, W_na_user,
                                     W_merge, b_merge, W_eattn, b_eattn,
                                     wq_eff, bq_eff, wk_eff, bk_eff, Wcomb, cmv);

    // weight pre-conversion to bf16 B-fragment layout (padded K)
    wconv_frag<<<64, 256, 0, stream>>>(W_nf_user, wub, 128, 300, 320);
    wconv_frag<<<64, 256, 0, stream>>>(W_nf_item, wib, 128, 200, 224);
    wconv_frag<<<32, 256, 0, stream>>>(W_ef,      web, 128,  64,  64);
    wconv_frag<<<64, 256, 0, stream>>>(W_v,       wvb, 256, 128, 128);

    // GEMM1: src_feat = x_user@W_nf_user^T + b + node_emb + edge_emb -> sf_b & esf_b
    gemm_stream<false, 8><<<dim3(1, 1563), 256, 0, stream>>>(
        x_user, wub, b_nf_user, node_emb_user, edge_emb,
        sf_b, esf_b, N_SRC, 300, 10, 128);
    // GEMM2: dst_feat = x_item@W_nf_item^T + b + edge_emb -> dsf_b
    gemm_stream<false, 8><<<dim3(1, 782), 256, 0, stream>>>(
        x_item, wib, b_nf_item, nullptr, edge_emb,
        dsf_b, nullptr, N_DST, 200, 7, 128);
    // GEMM3: P = exp(edge_feats@W_ef^T + b_ef) -> P_b
    gemm_stream<false, 8><<<dim3(1, 3125), 256, 0, stream>>>(
        edge_feats, web, b_ef, nullptr, nullptr,
        nullptr, P_b, NE, 64, 2, 128);
    // GEMM4: v = sf@W_v^T + b_v -> v_b (A is bf16, C=256 via NT=16)
    gemm_stream<true, 16><<<dim3(1, 1563), 256, 0, stream>>>(
        sf_b, wvb, b_v, nullptr, nullptr,
        v_b, nullptr, N_SRC, 128, 4, 256);

    // aq / ak via folded weights
    rowdot8_bf<<<25000, 256, 0, stream>>>(dsf_b, wq_eff, bq_eff, aq, N_DST);
    rowdot8_bf<<<50000, 256, 0, stream>>>(sf_b, wk_eff, bk_eff, ak, N_SRC);

    // CSR build
    hist_kernel<<<1563, 256, 0, stream>>>(dst_idx, cnt);
    blocksum_kernel<<<NSCAN, 256, 0, stream>>>(cnt, bsum);
    scanoff_kernel<<<1, 64, 0, stream>>>(bsum, boff);
    rowstart_kernel<<<NSCAN, 256, 0, stream>>>(cnt, boff, row_start, cursor);
    scatter_kernel<<<1563, 256, 0, stream>>>(dst_idx, cursor, eorder);

    // mega-fused gather + LN
    fused_gather2<<<25000, 256, 0, stream>>>(
        row_start, eorder, src_idx, P_b, esf_b, v_b, aq, ak,
        Wcomb, cmv, W_merge, ln_gamma, ln_beta, (float*)d_out);
}

// Round 6
// 849.770 us; speedup vs baseline: 3.8140x; 1.0268x over previous
//
#include <hip/hip_runtime.h>
#include <math.h>
#include <stdio.h>
#include <stdint.h>

#define N_SRC 200000
#define N_DST 100000
#define NE    400000
// IN=128, H=8, D=32, H*D=256

#define SCAN_CHUNK 1024
#define NSCAN ((N_DST + SCAN_CHUNK - 1) / SCAN_CHUNK)   // 98

typedef short bf16x8 __attribute__((ext_vector_type(8)));
typedef float f32x4 __attribute__((ext_vector_type(4)));

__device__ __forceinline__ float bflo(unsigned int u) { return __uint_as_float(u << 16); }
__device__ __forceinline__ float bfhi(unsigned int u) { return __uint_as_float(u & 0xFFFF0000u); }
__device__ __forceinline__ unsigned short f2bf(float f) {
    unsigned int u = __float_as_uint(f);
    u += 0x7FFFu + ((u >> 16) & 1u);       // round-to-nearest-even
    return (unsigned short)(u >> 16);
}
// pack two f32 -> (bf16(f1)<<16)|bf16(f0) by truncation: single v_perm_b32
__device__ __forceinline__ unsigned int packbf(float f0, float f1) {
    return __builtin_amdgcn_perm(__float_as_uint(f1), __float_as_uint(f0), 0x07060302u);
}

// ---------------------------------------------------------------------------
// Barrier-free streaming MFMA GEMM, DEPTH-2 register pipeline.
// out[n][c] = sum_k A[n][k]*W[c][k] (+bias[c]+add_c[c]+add_n[n][c]).
//  - each wave owns 32 rows (2 m-tiles) x NT col-tiles; A loads global->reg
//    (rows wave-private => A read exactly once), ping-pong buffers, prefetch
//    2 K-steps ahead so HBM latency hides under 2 steps of MFMA+VALU.
//  - W pre-converted to B-fragment layout: one coalesced dwordx4 per frag,
//    L2-resident, reloaded 2 steps ahead (L2 latency ~200cy << slack).
//  - bf16 pack via v_perm (truncate): 1 op / 2 values.
// A: f32 [N][K] (ABF=false) or bf16 [N][K] (ABF=true, K%32==0).
// ---------------------------------------------------------------------------
template<bool ABF, int NT>
__global__ __launch_bounds__(256) void gemm_stream(
    const void* __restrict__ Ap, const unsigned short* __restrict__ Wf,
    const float* __restrict__ bias, const float* __restrict__ add_n,
    const float* __restrict__ add_c,
    unsigned short* __restrict__ out_lin, unsigned short* __restrict__ out_exp,
    int N, int K, int KS, int C)
{
    const int tid  = threadIdx.x;
    const int lane = tid & 63;
    const int wv   = tid >> 6;
    const int fr   = lane & 15;
    const int fq   = lane >> 4;
    const int row0 = blockIdx.y * 128 + wv * 32;
    const int c0   = blockIdx.x * (NT * 16);
    const int nb0  = c0 >> 4;

    long ar[2];
    {
        int r0 = row0 + fr;       if (r0 >= N) r0 = N - 1;
        int r1 = row0 + 16 + fr;  if (r1 >= N) r1 = N - 1;
        ar[0] = (long)r0 * K;
        ar[1] = (long)r1 * K;
    }
    const float* Af = (const float*)Ap;
    const unsigned short* Ab = (const unsigned short*)Ap;

    f32x4 acc[2][NT];
#pragma unroll
    for (int m = 0; m < 2; ++m)
#pragma unroll
        for (int n = 0; n < NT; ++n) acc[m][n] = (f32x4){0.f, 0.f, 0.f, 0.f};

    // ping-pong register buffers (all statically indexed)
    float4 aA[2][2], aB[2][2];     // f32 A
    uint4  abA[2],  abB[2];        // bf16 A
    uint4  bA[NT],  bB[NT];        // B fragments

    auto loadA = [&](int ks, float4 (&pa)[2][2], uint4 (&pab)[2]) {
        const int kk = ks * 32 + fq * 8;
        if (ABF) {
#pragma unroll
            for (int m = 0; m < 2; ++m)
                pab[m] = *(const uint4*)&Ab[ar[m] + kk];
        } else {
            if (kk + 8 <= K) {
#pragma unroll
                for (int m = 0; m < 2; ++m) {
                    const float* p = &Af[ar[m] + kk];
                    pa[m][0] = *(const float4*)p;
                    pa[m][1] = *(const float4*)(p + 4);
                }
            } else {
#pragma unroll
                for (int m = 0; m < 2; ++m) {
                    float t[8];
#pragma unroll
                    for (int j = 0; j < 8; ++j)
                        t[j] = (kk + j < K) ? Af[ar[m] + kk + j] : 0.f;
                    pa[m][0] = make_float4(t[0], t[1], t[2], t[3]);
                    pa[m][1] = make_float4(t[4], t[5], t[6], t[7]);
                }
            }
        }
    };
    auto loadB = [&](int ks, uint4 (&pb)[NT]) {
#pragma unroll
        for (int n = 0; n < NT; ++n)
            pb[n] = *(const uint4*)&Wf[(size_t)((((nb0 + n) * KS + ks) << 6) | lane) << 3];
    };
    auto step = [&](int ks, float4 (&pa)[2][2], uint4 (&pab)[2], uint4 (&pb)[NT]) {
        bf16x8 ca[2];
        if (ABF) {
#pragma unroll
            for (int m = 0; m < 2; ++m) ca[m] = *(bf16x8*)&pab[m];
        } else {
#pragma unroll
            for (int m = 0; m < 2; ++m) {
                uint4 u;
                u.x = packbf(pa[m][0].x, pa[m][0].y);
                u.y = packbf(pa[m][0].z, pa[m][0].w);
                u.z = packbf(pa[m][1].x, pa[m][1].y);
                u.w = packbf(pa[m][1].z, pa[m][1].w);
                ca[m] = *(bf16x8*)&u;
            }
        }
        if (ks + 2 < KS) loadA(ks + 2, pa, pab);   // A prefetch before MFMAs
#pragma unroll
        for (int m = 0; m < 2; ++m)
#pragma unroll
            for (int n = 0; n < NT; ++n)
                acc[m][n] = __builtin_amdgcn_mfma_f32_16x16x32_bf16(ca[m], *(bf16x8*)&pb[n], acc[m][n], 0, 0, 0);
        if (ks + 2 < KS) loadB(ks + 2, pb);        // B reload after consumption
    };

    loadA(0, aA, abA); loadB(0, bA);
    if (KS > 1) { loadA(1, aB, abB); loadB(1, bB); }
    for (int ks = 0; ks < KS; ks += 2) {
        step(ks, aA, abA, bA);
        if (ks + 1 < KS) step(ks + 1, aB, abB, bB);
    }

    // epilogue: D col = lane&15, row = (lane>>4)*4 + reg (measured m89/m91)
    float bc[NT];
#pragma unroll
    for (int n = 0; n < NT; ++n) {
        int col = c0 + n * 16 + fr;
        float b = 0.f;
        if (bias)  b += bias[col];
        if (add_c) b += add_c[col];
        bc[n] = b;
    }
#pragma unroll
    for (int m = 0; m < 2; ++m) {
#pragma unroll
        for (int j = 0; j < 4; ++j) {
            int row = row0 + m * 16 + fq * 4 + j;
            if (row >= N) continue;
#pragma unroll
            for (int n = 0; n < NT; ++n) {
                int col = c0 + n * 16 + fr;
                float v = acc[m][n][j] + bc[n];
                if (add_n) v += add_n[(long)row * C + col];
                long o = (long)row * C + col;
                if (out_lin) out_lin[o] = f2bf(v);
                if (out_exp) out_exp[o] = f2bf(expf(v));
            }
        }
    }
}

// ---------------------------------------------------------------------------
// Weight f32 [C][K] -> bf16 B-fragment layout, zero-padded to Kp (KS=Kp/32):
// dst[((n*KS+ks)*64+l)*8 + j] = W[n*16 + (l&15)][ks*32 + (l>>4)*8 + j]
// ---------------------------------------------------------------------------
__global__ void wconv_frag(const float* __restrict__ src, unsigned short* __restrict__ dst,
                           int C, int K, int Kp)
{
    int KS = Kp >> 5;
    int total = C * Kp;
    for (int i = blockIdx.x * blockDim.x + threadIdx.x; i < total; i += gridDim.x * blockDim.x) {
        int j  = i & 7;
        int l  = (i >> 3) & 63;
        int t  = i >> 9;
        int ks = t % KS;
        int n  = t / KS;
        int col = n * 16 + (l & 15);
        int k   = ks * 32 + ((l >> 4) << 3) + j;
        dst[i] = (k < K) ? f2bf(src[(long)col * K + k]) : (unsigned short)0;
    }
}

// ---------------------------------------------------------------------------
// Setup: fold W_na into Q/K (wq_eff/wk_eff [8][128]), fold W_merge x W_eattn
// into Wcomb [8][128], cm[8] = b_merge + W_merge[:,8:] . b_eattn
// ---------------------------------------------------------------------------
__global__ void eff_setup(const float* __restrict__ Wq, const float* __restrict__ bq,
                          const float* __restrict__ na_item,
                          const float* __restrict__ Wk, const float* __restrict__ bk,
                          const float* __restrict__ na_user,
                          const float* __restrict__ W_merge, const float* __restrict__ b_merge,
                          const float* __restrict__ W_eattn, const float* __restrict__ b_eattn,
                          float* __restrict__ wq_eff, float* __restrict__ bq_eff,
                          float* __restrict__ wk_eff, float* __restrict__ bk_eff,
                          float* __restrict__ Wcomb, float* __restrict__ cmv)
{
    int tid = threadIdx.x;
    for (int idx = tid; idx < 1024; idx += 256) {
        int h = idx >> 7, k = idx & 127;
        float s1 = 0.f, s2 = 0.f, s3 = 0.f;
        for (int d = 0; d < 32; ++d) {
            s1 += Wq[(h * 32 + d) * 128 + k] * na_item[d];
            s2 += Wk[(h * 32 + d) * 128 + k] * na_user[d];
        }
        for (int j = 0; j < 8; ++j)
            s3 += W_merge[h * 16 + 8 + j] * W_eattn[j * 128 + k];
        wq_eff[idx] = s1;
        wk_eff[idx] = s2;
        Wcomb[idx]  = s3;
    }
    if (tid < 8) {
        float s1 = 0.f, s2 = 0.f, s3 = b_merge[tid];
        for (int d = 0; d < 32; ++d) {
            s1 += bq[tid * 32 + d] * na_item[d];
            s2 += bk[tid * 32 + d] * na_user[d];
        }
        for (int j = 0; j < 8; ++j) s3 += W_merge[tid * 16 + 8 + j] * b_eattn[j];
        bq_eff[tid] = s1;
        bk_eff[tid] = s2;
        cmv[tid]    = s3;
    }
}

// ---------------------------------------------------------------------------
// Wave-per-row 8-head dot from bf16 features, transpose-butterfly reduce.
// ---------------------------------------------------------------------------
__global__ __launch_bounds__(256) void rowdot8_bf(
    const unsigned short* __restrict__ feat, const float* __restrict__ weff,
    const float* __restrict__ beff, float* __restrict__ out, int N)
{
    int gw   = (blockIdx.x * blockDim.x + threadIdx.x) >> 6;
    int lane = threadIdx.x & 63;
    if (gw >= N) return;
    int ch = lane * 2;
    unsigned int u = *(const unsigned int*)&feat[(long)gw * 128 + ch];
    float x0 = bflo(u), x1 = bfhi(u);
    float part[8];
#pragma unroll
    for (int h = 0; h < 8; ++h)
        part[h] = x0 * weff[h * 128 + ch] + x1 * weff[h * 128 + ch + 1];
    int b0 = lane & 1, b1 = (lane >> 1) & 1, b2 = (lane >> 2) & 1;
    float u0 = (b0 ? part[1] : part[0]) + __shfl_xor(b0 ? part[0] : part[1], 1);
    float u1 = (b0 ? part[3] : part[2]) + __shfl_xor(b0 ? part[2] : part[3], 1);
    float u2 = (b0 ? part[5] : part[4]) + __shfl_xor(b0 ? part[4] : part[5], 1);
    float u3 = (b0 ? part[7] : part[6]) + __shfl_xor(b0 ? part[6] : part[7], 1);
    float w0 = (b1 ? u1 : u0) + __shfl_xor(b1 ? u0 : u1, 2);
    float w1 = (b1 ? u3 : u2) + __shfl_xor(b1 ? u2 : u3, 2);
    float ts = (b2 ? w1 : w0) + __shfl_xor(b2 ? w0 : w1, 4);
    ts += __shfl_xor(ts, 8);
    ts += __shfl_xor(ts, 16);
    ts += __shfl_xor(ts, 32);
    if (lane < 8) out[(long)gw * 8 + lane] = ts + beff[lane];
}

// ---------------------------------------------------------------------------
// CSR build: histogram -> two-level scan -> scatter
// ---------------------------------------------------------------------------
__global__ void hist_kernel(const int* __restrict__ dst_idx, int* __restrict__ cnt)
{
    int e = blockIdx.x * blockDim.x + threadIdx.x;
    if (e < NE) atomicAdd(&cnt[dst_idx[e]], 1);
}

__global__ __launch_bounds__(256) void blocksum_kernel(const int* __restrict__ cnt,
                                                       int* __restrict__ bsum)
{
    __shared__ int sm[256];
    int b = blockIdx.x, t = threadIdx.x;
    int s = 0;
    for (int i = t; i < SCAN_CHUNK; i += 256) {
        int idx = b * SCAN_CHUNK + i;
        if (idx < N_DST) s += cnt[idx];
    }
    sm[t] = s; __syncthreads();
    for (int off = 128; off > 0; off >>= 1) {
        if (t < off) sm[t] += sm[t + off];
        __syncthreads();
    }
    if (t == 0) bsum[b] = sm[0];
}

__global__ void scanoff_kernel(const int* __restrict__ bsum, int* __restrict__ boff)
{
    if (threadIdx.x == 0) {
        int r = 0;
        for (int i = 0; i < NSCAN; ++i) { boff[i] = r; r += bsum[i]; }
    }
}

__global__ __launch_bounds__(256) void rowstart_kernel(
    const int* __restrict__ cnt, const int* __restrict__ boff,
    int* __restrict__ row_start, int* __restrict__ cursor)
{
    __shared__ int sm[256];
    int b = blockIdx.x, t = threadIdx.x;
    int base = b * SCAN_CHUNK + t * 4;
    int c[4]; int tot = 0;
#pragma unroll
    for (int j = 0; j < 4; ++j) {
        int idx = base + j;
        c[j] = (idx < N_DST) ? cnt[idx] : 0;
        tot += c[j];
    }
    sm[t] = tot; __syncthreads();
    for (int off = 1; off < 256; off <<= 1) {
        int v = (t >= off) ? sm[t - off] : 0;
        __syncthreads();
        sm[t] += v;
        __syncthreads();
    }
    int run = sm[t] - tot + boff[b];
#pragma unroll
    for (int j = 0; j < 4; ++j) {
        int idx = base + j;
        if (idx < N_DST) { row_start[idx] = run; cursor[idx] = run; run += c[j]; }
    }
    if (b == 0 && t == 0) row_start[N_DST] = NE;
}

__global__ void scatter_kernel(const int* __restrict__ dst_idx,
                               int* __restrict__ cursor, int* __restrict__ eorder)
{
    int e = blockIdx.x * blockDim.x + threadIdx.x;
    if (e >= NE) return;
    int pos = atomicAdd(&cursor[dst_idx[e]], 1);
    eorder[pos] = e;
}

// ---------------------------------------------------------------------------
// Mega-fused gather v2: one wave per dst. z = P * esf (precomputed exps);
// Wcomb-folded temp path; transpose-butterfly reduce (10 shfl); LN epilogue.
// ---------------------------------------------------------------------------
__global__ __launch_bounds__(256) void fused_gather2(
    const int* __restrict__ row_start, const int* __restrict__ eorder,
    const int* __restrict__ src_idx,
    const unsigned short* __restrict__ Pb, const unsigned short* __restrict__ esfb,
    const unsigned short* __restrict__ vb,
    const float* __restrict__ aq, const float* __restrict__ ak,
    const float* __restrict__ Wcomb, const float* __restrict__ cmv,
    const float* __restrict__ W_merge,
    const float* __restrict__ ln_gamma, const float* __restrict__ ln_beta,
    float* __restrict__ out)
{
    int gw   = (blockIdx.x * blockDim.x + threadIdx.x) >> 6;
    int lane = threadIdx.x & 63;
    if (gw >= N_DST) return;
    const int dst = gw;
    const int r0 = row_start[dst], r1 = row_start[dst + 1];
    const int ch = lane * 2;
    const int hl = lane & 7;
    const int g  = lane >> 3;
    const float rsc = 0.17677669529663687f;   // 1/sqrt(32)

    float wc0[8], wc1[8];
#pragma unroll
    for (int h = 0; h < 8; ++h) {
        wc0[h] = Wcomb[h * 128 + ch];
        wc1[h] = Wcomb[h * 128 + ch + 1];
    }
    const float wself = W_merge[g * 16 + hl];
    const float cmg   = cmv[g];
    const float aqh   = aq[(long)dst * 8 + hl];

    // ---- pass 1: denominators ----
    float s1x = 0.f, s1y = 0.f, s2l = 0.f;
    int eo = 0, src = 0;
    if (r0 < r1) { eo = eorder[r0]; src = src_idx[eo]; }
    for (int j = r0; j < r1; ++j) {
        int eo_n = 0, src_n = 0;
        if (j + 1 < r1) { eo_n = eorder[j + 1]; src_n = src_idx[eo_n]; }
        unsigned int pe = *(const unsigned int*)&Pb[(long)eo * 128 + ch];
        unsigned int se = *(const unsigned int*)&esfb[(long)src * 128 + ch];
        float akh = ak[(long)src * 8 + hl];
        s1x += bflo(pe) * bflo(se);
        s1y += bfhi(pe) * bfhi(se);
        s2l += expf((akh + aqh) * rsc);
        eo = eo_n; src = src_n;
    }
    const float i1x = 1.0f / s1x, i1y = 1.0f / s1y, i2 = 1.0f / s2l;

    // ---- pass 2: attention + aggregate ----
    float ax = 0.f, ay = 0.f, az = 0.f, aw = 0.f;
    if (r0 < r1) { eo = eorder[r0]; src = src_idx[eo]; }
    for (int j = r0; j < r1; ++j) {
        int eo_n = 0, src_n = 0;
        if (j + 1 < r1) { eo_n = eorder[j + 1]; src_n = src_idx[eo_n]; }
        unsigned int pe = *(const unsigned int*)&Pb[(long)eo * 128 + ch];
        unsigned int se = *(const unsigned int*)&esfb[(long)src * 128 + ch];
        float akh = ak[(long)src * 8 + hl];
        uint2 vv = *(const uint2*)&vb[(long)src * 256 + lane * 4];
        float t0 = bflo(pe) * bflo(se) * i1x;
        float t1 = bfhi(pe) * bfhi(se) * i1y;
        float part[8];
#pragma unroll
        for (int h = 0; h < 8; ++h) part[h] = t0 * wc0[h] + t1 * wc1[h];
        // transpose-butterfly: 8 values over 64 lanes in 10 shfl
        int b0 = lane & 1, b1 = (lane >> 1) & 1, b2 = (lane >> 2) & 1;
        float u0 = (b0 ? part[1] : part[0]) + __shfl_xor(b0 ? part[0] : part[1], 1);
        float u1 = (b0 ? part[3] : part[2]) + __shfl_xor(b0 ? part[2] : part[3], 1);
        float u2 = (b0 ? part[5] : part[4]) + __shfl_xor(b0 ? part[4] : part[5], 1);
        float u3 = (b0 ? part[7] : part[6]) + __shfl_xor(b0 ? part[6] : part[7], 1);
        float w0 = (b1 ? u1 : u0) + __shfl_xor(b1 ? u0 : u1, 2);
        float w1 = (b1 ? u3 : u2) + __shfl_xor(b1 ? u2 : u3, 2);
        float ts = (b2 ? w1 : w0) + __shfl_xor(b2 ? w0 : w1, 4);
        ts += __shfl_xor(ts, 8);
        ts += __shfl_xor(ts, 16);
        ts += __shfl_xor(ts, 32);
        // self part: group-local 3-shfl reduce (head g = lane>>3)
        float sa = expf((akh + aqh) * rsc) * i2;
        float ms = wself * sa;
        ms += __shfl_xor(ms, 1);
        ms += __shfl_xor(ms, 2);
        ms += __shfl_xor(ms, 4);
        float mm = cmg + ms + __shfl(ts, g);
        ax += mm * bflo(vv.x); ay += mm * bfhi(vv.x);
        az += mm * bflo(vv.y); aw += mm * bfhi(vv.y);
        eo = eo_n; src = src_n;
    }

    // ---- LayerNorm epilogue ----
    float s = ax + ay + az + aw;
    float q = ax * ax + ay * ay + az * az + aw * aw;
#pragma unroll
    for (int off = 32; off > 0; off >>= 1) {
        s += __shfl_xor(s, off);
        q += __shfl_xor(q, off);
    }
    float mu  = s * (1.0f / 256.0f);
    float var = q * (1.0f / 256.0f) - mu * mu;
    float inv = rsqrtf(var + 1e-5f);
    float4 gg = *(const float4*)&ln_gamma[lane * 4];
    float4 bb = *(const float4*)&ln_beta[lane * 4];
    float4 o;
    o.x = (ax - mu) * inv * gg.x + bb.x;
    o.y = (ay - mu) * inv * gg.y + bb.y;
    o.z = (az - mu) * inv * gg.z + bb.z;
    o.w = (aw - mu) * inv * gg.w + bb.w;
    *(float4*)&out[(long)dst * 256 + lane * 4] = o;
}

// ---------------------------------------------------------------------------
extern "C" void kernel_launch(void* const* d_in, const int* in_sizes, int n_in,
                              void* d_out, int out_size, void* d_ws, size_t ws_size,
                              hipStream_t stream)
{
    const float* x_user        = (const float*)d_in[0];
    const float* x_item        = (const float*)d_in[1];
    const float* node_emb_user = (const float*)d_in[2];
    const float* edge_emb      = (const float*)d_in[3];
    const float* edge_feats    = (const float*)d_in[4];
    const int*   src_idx       = (const int*)d_in[5];
    const int*   dst_idx       = (const int*)d_in[6];
    const float* W_nf_user     = (const float*)d_in[7];
    const float* b_nf_user     = (const float*)d_in[8];
    const float* W_nf_item     = (const float*)d_in[9];
    const float* b_nf_item     = (const float*)d_in[10];
    const float* W_ef          = (const float*)d_in[11];
    const float* b_ef          = (const float*)d_in[12];
    const float* W_eattn       = (const float*)d_in[13];
    const float* b_eattn       = (const float*)d_in[14];
    const float* W_merge       = (const float*)d_in[15];
    const float* b_merge       = (const float*)d_in[16];
    const float* W_q           = (const float*)d_in[17];
    const float* b_q           = (const float*)d_in[18];
    const float* W_k           = (const float*)d_in[19];
    const float* b_k           = (const float*)d_in[20];
    const float* W_v           = (const float*)d_in[21];
    const float* b_v           = (const float*)d_in[22];
    const float* W_na_user     = (const float*)d_in[23];
    const float* W_na_item     = (const float*)d_in[24];
    const float* ln_gamma      = (const float*)d_in[25];
    const float* ln_beta       = (const float*)d_in[26];

    unsigned short* us   = (unsigned short*)d_ws;
    unsigned short* sf_b  = us;                    // 25,600,000  bf16 src_feat
    unsigned short* esf_b = sf_b + 25600000;       // 25,600,000  bf16 exp(src_feat)
    unsigned short* dsf_b = esf_b + 25600000;      // 12,800,000  bf16 dst_feat
    unsigned short* P_b   = dsf_b + 12800000;      // 51,200,000  bf16 exp(ef)
    unsigned short* v_b   = P_b + 51200000;        // 51,200,000  bf16 v
    float* fz     = (float*)(v_b + 51200000);
    float* aq     = fz;                            // 800,000
    float* ak     = aq + 800000;                   // 1,600,000
    float* wq_eff = ak + 1600000;                  // 1024
    float* wk_eff = wq_eff + 1024;                 // 1024
    float* bq_eff = wk_eff + 1024;                 // 16
    float* bk_eff = bq_eff + 16;                   // 16
    float* Wcomb  = bk_eff + 16;                   // 1024
    float* cmv    = Wcomb + 1024;                  // 8
    int*   cnt       = (int*)(cmv + 8);            // N_DST
    int*   bsum      = cnt + N_DST;                // 128
    int*   boff      = bsum + 128;                 // 128
    int*   row_start = boff + 128;                 // N_DST + 1
    int*   cursor    = row_start + N_DST + 1;      // N_DST
    int*   eorder    = cursor + N_DST;             // NE
    // W fragment buffers (16B-aligned for dwordx4 loads)
    unsigned short* wub = (unsigned short*)(((uintptr_t)(eorder + NE) + 15) & ~(uintptr_t)15);
    unsigned short* wib = wub + 128 * 320;
    unsigned short* web = wib + 128 * 224;
    unsigned short* wvb = web + 128 * 64;
    size_t needed = (size_t)((char*)(wvb + 256 * 128) - (char*)d_ws);
    if (ws_size < needed) {
        fprintf(stderr, "kernel_launch: ws_size %zu < needed %zu\n", ws_size, needed);
        return;
    }

    hipMemsetAsync(cnt, 0, N_DST * sizeof(int), stream);

    eff_setup<<<1, 256, 0, stream>>>(W_q, b_q, W_na_item, W_k, b_k, W_na_user,
                                     W_merge, b_merge, W_eattn, b_eattn,
                                     wq_eff, bq_eff, wk_eff, bk_eff, Wcomb, cmv);

    // weight pre-conversion to bf16 B-fragment layout (padded K)
    wconv_frag<<<64, 256, 0, stream>>>(W_nf_user, wub, 128, 300, 320);
    wconv_frag<<<64, 256, 0, stream>>>(W_nf_item, wib, 128, 200, 224);
    wconv_frag<<<32, 256, 0, stream>>>(W_ef,      web, 128,  64,  64);
    wconv_frag<<<64, 256, 0, stream>>>(W_v,       wvb, 256, 128, 128);

    // GEMM1: src_feat = x_user@W_nf_user^T + b + node_emb + edge_emb -> sf_b & esf_b
    gemm_stream<false, 8><<<dim3(1, 1563), 256, 0, stream>>>(
        x_user, wub, b_nf_user, node_emb_user, edge_emb,
        sf_b, esf_b, N_SRC, 300, 10, 128);
    // GEMM2: dst_feat = x_item@W_nf_item^T + b + edge_emb -> dsf_b
    gemm_stream<false, 8><<<dim3(1, 782), 256, 0, stream>>>(
        x_item, wib, b_nf_item, nullptr, edge_emb,
        dsf_b, nullptr, N_DST, 200, 7, 128);
    // GEMM3: P = exp(edge_feats@W_ef^T + b_ef) -> P_b
    gemm_stream<false, 8><<<dim3(1, 3125), 256, 0, stream>>>(
        edge_feats, web, b_ef, nullptr, nullptr,
        nullptr, P_b, NE, 64, 2, 128);
    // GEMM4: v = sf@W_v^T + b_v -> v_b (A bf16; C=256 split over grid.x=2)
    gemm_stream<true, 8><<<dim3(2, 1563), 256, 0, stream>>>(
        sf_b, wvb, b_v, nullptr, nullptr,
        v_b, nullptr, N_SRC, 128, 4, 256);

    // aq / ak via folded weights
    rowdot8_bf<<<25000, 256, 0, stream>>>(dsf_b, wq_eff, bq_eff, aq, N_DST);
    rowdot8_bf<<<50000, 256, 0, stream>>>(sf_b, wk_eff, bk_eff, ak, N_SRC);

    // CSR build
    hist_kernel<<<1563, 256, 0, stream>>>(dst_idx, cnt);
    blocksum_kernel<<<NSCAN, 256, 0, stream>>>(cnt, bsum);
    scanoff_kernel<<<1, 64, 0, stream>>>(bsum, boff);
    rowstart_kernel<<<NSCAN, 256, 0, stream>>>(cnt, boff, row_start, cursor);
    scatter_kernel<<<1563, 256, 0, stream>>>(dst_idx, cursor, eorder);

    // mega-fused gather + LN
    fused_gather2<<<25000, 256, 0, stream>>>(
        row_start, eorder, src_idx, P_b, esf_b, v_b, aq, ak,
        Wcomb, cmv, W_merge, ln_gamma, ln_beta, (float*)d_out);
}